// Round 4
// baseline (1217.696 us; speedup 1.0000x reference)
//
#include <hip/hip_runtime.h>
#include <hip/hip_bf16.h>
#include <math.h>

#define B_ 8
#define C_ 256
#define H_ 64
#define W_ 64
#define N_ 4096
#define M_ 1024
#define HW_ 4096

typedef __attribute__((ext_vector_type(8))) short short8;
typedef __attribute__((ext_vector_type(4))) float f32x4;

__device__ __forceinline__ unsigned short f2bf(float x) {
    unsigned u = __float_as_uint(x);
    u += 0x7fffu + ((u >> 16) & 1u);          // round-to-nearest-even
    return (unsigned short)(u >> 16);
}
__device__ __forceinline__ float bf2f(unsigned short h) {
    return __uint_as_float(((unsigned)h) << 16);
}

// ---------------------------------------------------------------------------
// Split Wq [256co][256ci][3][3] fp32 -> per-tap bf16 hi/lo [9][256co][256ci].
__global__ __launch_bounds__(256) void split_w_tap(
    const float* __restrict__ Wq, unsigned short* __restrict__ wtH,
    unsigned short* __restrict__ wtL)
{
    int co = blockIdx.x, ci = threadIdx.x;
    const float* wp = Wq + ((size_t)co * 256 + ci) * 9;
    #pragma unroll
    for (int tap = 0; tap < 9; ++tap) {
        float v = wp[tap];
        unsigned short h = f2bf(v), l = f2bf(v - bf2f(h));
        size_t o = ((size_t)tap << 16) + ((size_t)co << 8) + ci;
        wtH[o] = h; wtL[o] = l;
    }
}

// Split W [256co][256ci][2][2] fp32 -> per-tap bf16 hi/lo [4][256co][256ci].
__global__ __launch_bounds__(256) void split_w2(
    const float* __restrict__ Wsrc, unsigned short* __restrict__ wH,
    unsigned short* __restrict__ wL)
{
    int co = blockIdx.x, ci = threadIdx.x;
    const float* wp = Wsrc + ((size_t)co * 256 + ci) * 4;
    #pragma unroll
    for (int tap = 0; tap < 4; ++tap) {
        float v = wp[tap];
        unsigned short h = f2bf(v), l = f2bf(v - bf2f(h));
        size_t o = ((size_t)tap << 16) + ((size_t)co << 8) + ci;
        wH[o] = h; wL[o] = l;
    }
}

// ---------------------------------------------------------------------------
// Transpose+split x [8][256][64][64] fp32 -> padded NHWC bf16 hi/lo
// [8][66][66][256] (halo pre-zeroed by memset). LDS-tiled transpose.
__global__ __launch_bounds__(256) void split_x_pad(
    const float* __restrict__ x, unsigned short* __restrict__ xpH,
    unsigned short* __restrict__ xpL)
{
    __shared__ float tile[64][65];
    int blk = blockIdx.x;            // b*64 + h
    int b = blk >> 6, h = blk & 63;
    int t = threadIdx.x;
    const float* xb = x + ((size_t)b << 20) + (size_t)h * 64;
    size_t obase = (((size_t)b * 4356) + (size_t)(h + 1) * 66 + 1) * 256;
    unsigned short* oH = xpH + obase;
    unsigned short* oL = xpL + obase;
    for (int cc = 0; cc < 256; cc += 64) {
        int wi = t & 63, cq = t >> 6;
        #pragma unroll
        for (int r = 0; r < 16; ++r) {
            int cl = cq * 16 + r;
            tile[cl][wi] = xb[((size_t)(cc + cl)) * 4096 + wi];
        }
        __syncthreads();
        int cl = t & 63, wq = t >> 6;
        #pragma unroll
        for (int r = 0; r < 16; ++r) {
            int wwi = wq * 16 + r;
            float v = tile[cl][wwi];
            unsigned short hh = f2bf(v), lo = f2bf(v - bf2f(hh));
            size_t o = (size_t)wwi * 256 + cc + cl;
            oH[o] = hh; oL[o] = lo;
        }
        __syncthreads();
    }
}

// Transpose+split y (4-batch half) fp32 -> NHWC bf16 hi/lo [4][64][64][256].
__global__ __launch_bounds__(256) void split_y_t(
    const float* __restrict__ y, unsigned short* __restrict__ yTh,
    unsigned short* __restrict__ yTl, int b0)
{
    __shared__ float tile[64][65];
    int blk = blockIdx.x;            // bl*64 + h, bl in [0,4)
    int bl = blk >> 6, h = blk & 63;
    int t = threadIdx.x;
    const float* yb = y + ((size_t)(b0 + bl) << 20) + (size_t)h * 64;
    size_t obase = (((size_t)bl << 12) + (size_t)h * 64) * 256;
    unsigned short* oH = yTh + obase;
    unsigned short* oL = yTl + obase;
    for (int cc = 0; cc < 256; cc += 64) {
        int wi = t & 63, cq = t >> 6;
        #pragma unroll
        for (int r = 0; r < 16; ++r) {
            int cl = cq * 16 + r;
            tile[cl][wi] = yb[((size_t)(cc + cl)) * 4096 + wi];
        }
        __syncthreads();
        int cl = t & 63, wq = t >> 6;
        #pragma unroll
        for (int r = 0; r < 16; ++r) {
            int wwi = wq * 16 + r;
            float v = tile[cl][wwi];
            unsigned short hh = f2bf(v), lo = f2bf(v - bf2f(hh));
            size_t o = (size_t)wwi * 256 + cc + cl;
            oH[o] = hh; oL[o] = lo;
        }
        __syncthreads();
    }
}

// ---------------------------------------------------------------------------
// conv 3x3 s1 p1 via MFMA: per-tap GEMM sum, split-bf16 3-term fp32 emulation.
__global__ __launch_bounds__(256, 2) void conv3x3_mfma(
    const unsigned short* __restrict__ xpH, const unsigned short* __restrict__ xpL,
    const unsigned short* __restrict__ wtH, const unsigned short* __restrict__ wtL,
    const float* __restrict__ bq,
    unsigned short* __restrict__ qH, unsigned short* __restrict__ qL)
{
    int blk = blockIdx.x;
    int bat = blk & 7;
    int rest = blk >> 3;
    int cot = rest & 1;
    int pxt = rest >> 1;                  // 32 tiles of 128 px (2 rows of 64)
    int t = threadIdx.x;
    int wv = t >> 6;
    int wco = wv >> 1, wpx = wv & 1;
    int lane = t & 63;
    int ll = lane & 15, qd = lane >> 4;

    const int co0 = cot * 128 + wco * 64;
    const unsigned short* aHp[4]; const unsigned short* aLp[4];
    #pragma unroll
    for (int ib = 0; ib < 4; ++ib) {
        size_t o = ((size_t)(co0 + ib * 16 + ll)) * 256 + qd * 8;
        aHp[ib] = wtH + o; aLp[ib] = wtL + o;
    }
    const unsigned short* bHp[4]; const unsigned short* bLp[4];
    const int h0 = pxt * 2;
    #pragma unroll
    for (int jb = 0; jb < 4; ++jb) {
        int pxl = wpx * 64 + jb * 16 + ll;
        int hh = h0 + (pxl >> 6);
        int ww = pxl & 63;
        size_t o = ((size_t)bat * 4356 + (size_t)hh * 66 + ww) * 256 + qd * 8;
        bHp[jb] = xpH + o; bLp[jb] = xpL + o;
    }

    f32x4 acc[4][4];
    #pragma unroll
    for (int i = 0; i < 4; ++i)
        #pragma unroll
        for (int j = 0; j < 4; ++j) acc[i][j] = (f32x4){0.f, 0.f, 0.f, 0.f};

    int boff = 0;   // (kh*66+kw)*256 shorts
    int kw = 0;
    for (int tap = 0; tap < 9; ++tap) {
        const int aoff = tap << 16;
        #pragma unroll 2
        for (int ci0 = 0; ci0 < 256; ci0 += 32) {
            short8 avh[4], avl[4], bvh[4], bvl[4];
            #pragma unroll
            for (int ib = 0; ib < 4; ++ib) {
                avh[ib] = *(const short8*)(aHp[ib] + aoff + ci0);
                avl[ib] = *(const short8*)(aLp[ib] + aoff + ci0);
            }
            #pragma unroll
            for (int jb = 0; jb < 4; ++jb) {
                bvh[jb] = *(const short8*)(bHp[jb] + boff + ci0);
                bvl[jb] = *(const short8*)(bLp[jb] + boff + ci0);
            }
            #pragma unroll
            for (int ib = 0; ib < 4; ++ib)
                #pragma unroll
                for (int jb = 0; jb < 4; ++jb) {
                    f32x4 o = acc[ib][jb];
                    o = __builtin_amdgcn_mfma_f32_16x16x32_bf16(avh[ib], bvh[jb], o, 0, 0, 0);
                    o = __builtin_amdgcn_mfma_f32_16x16x32_bf16(avl[ib], bvh[jb], o, 0, 0, 0);
                    o = __builtin_amdgcn_mfma_f32_16x16x32_bf16(avh[ib], bvl[jb], o, 0, 0, 0);
                    acc[ib][jb] = o;
                }
        }
        kw++;
        boff += 256;
        if (kw == 3) { kw = 0; boff += 63 * 256; }
    }

    const int pxbase = pxt * 128 + wpx * 64;
    #pragma unroll
    for (int ib = 0; ib < 4; ++ib) {
        #pragma unroll
        for (int r = 0; r < 4; ++r) {
            int co = co0 + ib * 16 + qd * 4 + r;
            float bvv = bq[co];
            size_t rowo = ((size_t)(bat * 256 + co)) << 12;
            #pragma unroll
            for (int jb = 0; jb < 4; ++jb) {
                float v = acc[ib][jb][r] + bvv;
                unsigned short h = f2bf(v), l = f2bf(v - bf2f(h));
                size_t o = rowo + pxbase + jb * 16 + ll;
                qH[o] = h; qL[o] = l;
            }
        }
    }
}

// ---------------------------------------------------------------------------
// conv 2x2 s2 p0 via MFMA (k and v), 4-batch half. Grid 128 = 4 bat x 4 sel
// x 8 m-tiles. Block 256 = 4 waves (2co x 2m). fp32 out (pre-GN).
__global__ __launch_bounds__(256, 2) void conv2x2_mfma(
    const unsigned short* __restrict__ yTh, const unsigned short* __restrict__ yTl,
    const unsigned short* __restrict__ wkH, const unsigned short* __restrict__ wkL,
    const unsigned short* __restrict__ wvH, const unsigned short* __restrict__ wvL,
    const float* __restrict__ bk, const float* __restrict__ bv,
    float* __restrict__ kf, float* __restrict__ vf, int b0)
{
    int blk = blockIdx.x;
    int batl = blk & 3;
    int sel = (blk >> 2) & 3;
    int mt  = blk >> 4;                   // 0..7, 128 m each
    int t = threadIdx.x;
    int wv_ = t >> 6;
    int wco = wv_ >> 1, wpx = wv_ & 1;
    int lane = t & 63;
    int ll = lane & 15, qd = lane >> 4;

    const unsigned short* wtH_; const unsigned short* wtL_;
    const float* bias; float* dst; int co0;
    if (sel < 2) { wtH_ = wkH; wtL_ = wkL; bias = bk; dst = kf; co0 = sel * 128 + wco * 64; }
    else         { wtH_ = wvH; wtL_ = wvL; bias = bv; dst = vf; co0 = (sel - 2) * 128 + wco * 64; }

    const unsigned short* aHp[4]; const unsigned short* aLp[4];
    #pragma unroll
    for (int ib = 0; ib < 4; ++ib) {
        size_t o = ((size_t)(co0 + ib * 16 + ll)) * 256 + qd * 8;
        aHp[ib] = wtH_ + o; aLp[ib] = wtL_ + o;
    }
    const unsigned short* bHp[4]; const unsigned short* bLp[4];
    #pragma unroll
    for (int jb = 0; jb < 4; ++jb) {
        int m = mt * 128 + wpx * 64 + jb * 16 + ll;
        int mh = m >> 5, mw = m & 31;
        size_t o = (((size_t)batl << 12) + (size_t)(2 * mh) * 64 + 2 * mw) * 256 + qd * 8;
        bHp[jb] = yTh + o; bLp[jb] = yTl + o;
    }

    f32x4 acc[4][4];
    #pragma unroll
    for (int i = 0; i < 4; ++i)
        #pragma unroll
        for (int j = 0; j < 4; ++j) acc[i][j] = (f32x4){0.f, 0.f, 0.f, 0.f};

    #pragma unroll
    for (int tap = 0; tap < 4; ++tap) {
        const int aoff = tap << 16;
        const int boff = (((tap >> 1) * 64) + (tap & 1)) * 256;
        #pragma unroll 2
        for (int ci0 = 0; ci0 < 256; ci0 += 32) {
            short8 avh[4], avl[4], bvh[4], bvl[4];
            #pragma unroll
            for (int ib = 0; ib < 4; ++ib) {
                avh[ib] = *(const short8*)(aHp[ib] + aoff + ci0);
                avl[ib] = *(const short8*)(aLp[ib] + aoff + ci0);
            }
            #pragma unroll
            for (int jb = 0; jb < 4; ++jb) {
                bvh[jb] = *(const short8*)(bHp[jb] + boff + ci0);
                bvl[jb] = *(const short8*)(bLp[jb] + boff + ci0);
            }
            #pragma unroll
            for (int ib = 0; ib < 4; ++ib)
                #pragma unroll
                for (int jb = 0; jb < 4; ++jb) {
                    f32x4 o = acc[ib][jb];
                    o = __builtin_amdgcn_mfma_f32_16x16x32_bf16(avh[ib], bvh[jb], o, 0, 0, 0);
                    o = __builtin_amdgcn_mfma_f32_16x16x32_bf16(avl[ib], bvh[jb], o, 0, 0, 0);
                    o = __builtin_amdgcn_mfma_f32_16x16x32_bf16(avh[ib], bvl[jb], o, 0, 0, 0);
                    acc[ib][jb] = o;
                }
        }
    }

    const int mbase = mt * 128 + wpx * 64;
    #pragma unroll
    for (int ib = 0; ib < 4; ++ib) {
        #pragma unroll
        for (int r = 0; r < 4; ++r) {
            int co = co0 + ib * 16 + qd * 4 + r;
            float bvv = bias[co];
            float* op = dst + (((size_t)((b0 + batl) * 256 + co)) << 10) + mbase + ll;
            #pragma unroll
            for (int jb = 0; jb < 4; ++jb)
                op[jb * 16] = acc[ib][jb][r] + bvv;
        }
    }
}

// ---------------------------------------------------------------------------
// GroupNorm stats (fp32 input): one block per (batch, group).
__global__ __launch_bounds__(256) void gn_stats_kernel(
    const float* __restrict__ buf, float* __restrict__ stats, int S)
{
    int bg = blockIdx.x;
    const float4* p = (const float4*)(buf + (size_t)bg * 8 * S);
    int n4 = 2 * S;
    float s = 0.f, s2 = 0.f;
    for (int i = threadIdx.x; i < n4; i += 256) {
        float4 vv = p[i];
        s  += vv.x + vv.y + vv.z + vv.w;
        s2 += vv.x * vv.x + vv.y * vv.y + vv.z * vv.z + vv.w * vv.w;
    }
    for (int d = 1; d < 64; d <<= 1) { s += __shfl_xor(s, d); s2 += __shfl_xor(s2, d); }
    __shared__ float red[8];
    int w = threadIdx.x >> 6;
    if ((threadIdx.x & 63) == 0) { red[w] = s; red[w + 4] = s2; }
    __syncthreads();
    if (threadIdx.x == 0) {
        s  = red[0] + red[1] + red[2] + red[3];
        s2 = red[4] + red[5] + red[6] + red[7];
        float invn = 1.f / (float)(8 * S);
        float mean = s * invn;
        float var = s2 * invn - mean * mean;
        if (var < 0.f) var = 0.f;
        stats[bg * 2]     = mean;
        stats[bg * 2 + 1] = 1.f / sqrtf(var + 1e-5f);
    }
}

// GroupNorm stats from bf16 hi/lo pair (q path).
__global__ __launch_bounds__(256) void gn_stats_pair(
    const unsigned short* __restrict__ hi, const unsigned short* __restrict__ lo,
    float* __restrict__ stats, int S)
{
    int bg = blockIdx.x;
    const uint4* ph = (const uint4*)(hi + (size_t)bg * 8 * S);
    const uint4* pl = (const uint4*)(lo + (size_t)bg * 8 * S);
    int n8 = S;
    float s = 0.f, s2 = 0.f;
    for (int i = threadIdx.x; i < n8; i += 256) {
        uint4 a = ph[i], b2 = pl[i];
        unsigned ua[4] = {a.x, a.y, a.z, a.w}, ub[4] = {b2.x, b2.y, b2.z, b2.w};
        #pragma unroll
        for (int j = 0; j < 4; ++j) {
            float x0 = __uint_as_float(ua[j] << 16) + __uint_as_float(ub[j] << 16);
            float x1 = __uint_as_float(ua[j] & 0xffff0000u) + __uint_as_float(ub[j] & 0xffff0000u);
            s += x0 + x1;
            s2 += x0 * x0 + x1 * x1;
        }
    }
    for (int d = 1; d < 64; d <<= 1) { s += __shfl_xor(s, d); s2 += __shfl_xor(s2, d); }
    __shared__ float red[8];
    int w = threadIdx.x >> 6;
    if ((threadIdx.x & 63) == 0) { red[w] = s; red[w + 4] = s2; }
    __syncthreads();
    if (threadIdx.x == 0) {
        s  = red[0] + red[1] + red[2] + red[3];
        s2 = red[4] + red[5] + red[6] + red[7];
        float invn = 1.f / (float)(8 * S);
        float mean = s * invn;
        float var = s2 * invn - mean * mean;
        if (var < 0.f) var = 0.f;
        stats[bg * 2]     = mean;
        stats[bg * 2 + 1] = 1.f / sqrtf(var + 1e-5f);
    }
}

// GN + affine + SiLU (+extra scale) on bf16 pair, in place (q path, N=4096).
__global__ __launch_bounds__(256) void gn_silu_pair(
    unsigned short* __restrict__ hi, unsigned short* __restrict__ lo,
    const float* __restrict__ stats, const float* __restrict__ scale,
    const float* __restrict__ bias, float extra, int total8)
{
    int idx = blockIdx.x * 256 + threadIdx.x;
    if (idx >= total8) return;
    size_t e = (size_t)idx * 8;
    int c  = (int)((e >> 12) & 255);
    int gg = (int)(e >> 15);
    float mean = stats[gg * 2], rstd = stats[gg * 2 + 1];
    float a  = scale[c] * rstd;
    float bb = bias[c] - mean * a;
    uint4 uh = ((uint4*)hi)[idx], ul = ((uint4*)lo)[idx];
    unsigned ha[4] = {uh.x, uh.y, uh.z, uh.w}, la[4] = {ul.x, ul.y, ul.z, ul.w};
    unsigned oh[4], ol[4];
    #pragma unroll
    for (int j = 0; j < 4; ++j) {
        float x0 = __uint_as_float(ha[j] << 16) + __uint_as_float(la[j] << 16);
        float x1 = __uint_as_float(ha[j] & 0xffff0000u) + __uint_as_float(la[j] & 0xffff0000u);
        float y0 = x0 * a + bb, y1 = x1 * a + bb;
        float s0 = extra * y0 / (1.f + __expf(-y0));
        float s1 = extra * y1 / (1.f + __expf(-y1));
        unsigned short h0 = f2bf(s0), l0 = f2bf(s0 - bf2f(h0));
        unsigned short h1 = f2bf(s1), l1 = f2bf(s1 - bf2f(h1));
        oh[j] = h0 | ((unsigned)h1 << 16);
        ol[j] = l0 | ((unsigned)l1 << 16);
    }
    ((uint4*)hi)[idx] = make_uint4(oh[0], oh[1], oh[2], oh[3]);
    ((uint4*)lo)[idx] = make_uint4(ol[0], ol[1], ol[2], ol[3]);
}

// GN + affine + SiLU on fp32 v -> bf16 hi/lo pair, natural [C][M] layout.
__global__ __launch_bounds__(256) void gn_silu_split_v(
    const float* __restrict__ vf, unsigned short* __restrict__ hi,
    unsigned short* __restrict__ lo, const float* __restrict__ stats,
    const float* __restrict__ scale, const float* __restrict__ bias, int total8)
{
    int idx = blockIdx.x * 256 + threadIdx.x;
    if (idx >= total8) return;
    size_t e = (size_t)idx * 8;
    int c  = (int)((e >> 10) & 255);
    int gg = (int)(e >> 13);
    float mean = stats[gg * 2], rstd = stats[gg * 2 + 1];
    float a  = scale[c] * rstd;
    float bb = bias[c] - mean * a;
    float4 f0 = ((const float4*)vf)[idx * 2];
    float4 f1 = ((const float4*)vf)[idx * 2 + 1];
    float xs[8] = {f0.x, f0.y, f0.z, f0.w, f1.x, f1.y, f1.z, f1.w};
    unsigned oh[4], ol[4];
    #pragma unroll
    for (int j = 0; j < 4; ++j) {
        float y0 = xs[2 * j] * a + bb, y1 = xs[2 * j + 1] * a + bb;
        float s0 = y0 / (1.f + __expf(-y0));
        float s1 = y1 / (1.f + __expf(-y1));
        unsigned short h0 = f2bf(s0), l0 = f2bf(s0 - bf2f(h0));
        unsigned short h1 = f2bf(s1), l1 = f2bf(s1 - bf2f(h1));
        oh[j] = h0 | ((unsigned)h1 << 16);
        ol[j] = l0 | ((unsigned)l1 << 16);
    }
    ((uint4*)hi)[idx] = make_uint4(oh[0], oh[1], oh[2], oh[3]);
    ((uint4*)lo)[idx] = make_uint4(ol[0], ol[1], ol[2], ol[3]);
}

// GN + affine + SiLU on fp32 k -> TRANSPOSED bf16 hi/lo [B][M][C] (B-frag layout).
__global__ __launch_bounds__(256) void gn_silu_split_kT(
    const float* __restrict__ kf, unsigned short* __restrict__ th,
    unsigned short* __restrict__ tl, const float* __restrict__ stats,
    const float* __restrict__ scale, const float* __restrict__ bias)
{
    int bm = blockIdx.x;              // 8 batches * 128 m8-groups
    int b = bm >> 7, m8 = (bm & 127) * 8;
    int c = threadIdx.x;
    int gg = b * 32 + (c >> 3);
    float mean = stats[gg * 2], rstd = stats[gg * 2 + 1];
    float a  = scale[c] * rstd;
    float bb = bias[c] - mean * a;
    const float* src = kf + (((size_t)(b * 256 + c)) << 10) + m8;
    float4 f0 = *(const float4*)src;
    float4 f1 = *(const float4*)(src + 4);
    float xs[8] = {f0.x, f0.y, f0.z, f0.w, f1.x, f1.y, f1.z, f1.w};
    #pragma unroll
    for (int j = 0; j < 8; ++j) {
        float y = xs[j] * a + bb;
        float s = y / (1.f + __expf(-y));
        unsigned short h = f2bf(s), l = f2bf(s - bf2f(h));
        size_t o = ((size_t)b * M_ + m8 + j) * C_ + c;
        th[o] = h;
        tl[o] = l;
    }
}

// ---------------------------------------------------------------------------
// Fused flash attention, split-bf16 MFMA (3-term fp32 emulation).
// Grid 1024 = 8 bat x 128 n-tiles (32 q-rows). Block 256 = 4 waves:
// 2 q-waves x 2 m-half waves; in-LDS merge. launch_bounds(256,3) caps
// arch-regs at ~170 -> 3 waves/SIMD residency. Row-sum l accumulated via
// ones-column MFMA (no cross-lane sum reduce; l lands indexed by q-row=lane).
__global__ __launch_bounds__(256, 3) void attn_mfma(
    const unsigned short* __restrict__ qh, const unsigned short* __restrict__ qlo,
    const unsigned short* __restrict__ kth, const unsigned short* __restrict__ ktl,
    const unsigned short* __restrict__ vh, const unsigned short* __restrict__ vlo,
    const float* __restrict__ gamma, float* __restrict__ out)
{
    __shared__ __align__(16) unsigned short pH[4][16][40];
    __shared__ __align__(16) unsigned short pL[4][16][40];
    __shared__ float alphaS[4][16];
    __shared__ float mS[4][16];
    __shared__ float lS[2][16];
    __shared__ __align__(16) float oS[2][4][16][17];   // [wq][ctl][c-row][n-col]

    int blk = blockIdx.x;
    int bat = blk & 7;
    int nt  = blk >> 3;           // 0..127
    int t = threadIdx.x;
    int w = t >> 6;               // 0..3
    int wq = w & 1;
    int mhalf = w >> 1;
    int lane = t & 63;
    int ll = lane & 15;
    int qd = lane >> 4;
    int n0 = nt * 32 + wq * 16;

    short8 aqh[8], aql[8];
    {
        const unsigned short* qb1 = qh  + (size_t)bat * C_ * N_ + n0 + ll;
        const unsigned short* qb2 = qlo + (size_t)bat * C_ * N_ + n0 + ll;
        #pragma unroll
        for (int ks = 0; ks < 8; ++ks) {
            #pragma unroll
            for (int j = 0; j < 8; ++j) {
                size_t off = (size_t)(ks * 32 + qd * 8 + j) * N_;
                aqh[ks][j] = (short)qb1[off];
                aql[ks][j] = (short)qb2[off];
            }
        }
    }

    f32x4 oacc[16];
    #pragma unroll
    for (int i = 0; i < 16; ++i) oacc[i] = (f32x4){0.f, 0.f, 0.f, 0.f};
    f32x4 lacc = (f32x4){0.f, 0.f, 0.f, 0.f};
    float mrun[4] = {-3e38f, -3e38f, -3e38f, -3e38f};
    const short8 ones = (short8){16256, 16256, 16256, 16256, 16256, 16256, 16256, 16256};

    const unsigned short* ktbh = kth + (size_t)bat * M_ * C_ + (size_t)ll * C_ + qd * 8;
    const unsigned short* ktbl = ktl + (size_t)bat * M_ * C_ + (size_t)ll * C_ + qd * 8;
    const unsigned short* vbh  = vh  + (size_t)bat * C_ * M_ + (size_t)ll * M_ + qd * 8;
    const unsigned short* vbl  = vlo + (size_t)bat * C_ * M_ + (size_t)ll * M_ + qd * 8;

    const int mt0 = mhalf * 16;
    for (int mt = mt0; mt < mt0 + 16; ++mt) {
        int m0 = mt * 32;
        f32x4 s0 = {0.f, 0.f, 0.f, 0.f}, s1 = {0.f, 0.f, 0.f, 0.f};
        const unsigned short* k0h = ktbh + (size_t)m0 * C_;
        const unsigned short* k0l = ktbl + (size_t)m0 * C_;
        const unsigned short* k1h = k0h + 16 * C_;
        const unsigned short* k1l = k0l + 16 * C_;
        #pragma unroll
        for (int ks = 0; ks < 8; ++ks) {
            short8 b0h = *(const short8*)(k0h + ks * 32);
            short8 b0l = *(const short8*)(k0l + ks * 32);
            short8 b1h = *(const short8*)(k1h + ks * 32);
            short8 b1l = *(const short8*)(k1l + ks * 32);
            s0 = __builtin_amdgcn_mfma_f32_16x16x32_bf16(aqh[ks], b0h, s0, 0, 0, 0);
            s1 = __builtin_amdgcn_mfma_f32_16x16x32_bf16(aqh[ks], b1h, s1, 0, 0, 0);
            s0 = __builtin_amdgcn_mfma_f32_16x16x32_bf16(aql[ks], b0h, s0, 0, 0, 0);
            s1 = __builtin_amdgcn_mfma_f32_16x16x32_bf16(aql[ks], b1h, s1, 0, 0, 0);
            s0 = __builtin_amdgcn_mfma_f32_16x16x32_bf16(aqh[ks], b0l, s0, 0, 0, 0);
            s1 = __builtin_amdgcn_mfma_f32_16x16x32_bf16(aqh[ks], b1l, s1, 0, 0, 0);
        }
        // online softmax: max-reduce only (row-sum l comes from ones-MFMA in PV)
        float alpha4[4];
        #pragma unroll
        for (int r = 0; r < 4; ++r) {
            float mx = fmaxf(s0[r], s1[r]);
            mx = fmaxf(mx, __shfl_xor(mx, 1));
            mx = fmaxf(mx, __shfl_xor(mx, 2));
            mx = fmaxf(mx, __shfl_xor(mx, 4));
            mx = fmaxf(mx, __shfl_xor(mx, 8));
            float mn = fmaxf(mrun[r], mx);
            float al = __expf(mrun[r] - mn);
            mrun[r] = mn;
            float p0 = __expf(s0[r] - mn);
            float p1 = __expf(s1[r] - mn);
            alpha4[r] = al;
            unsigned short h0 = f2bf(p0), l0 = f2bf(p0 - bf2f(h0));
            unsigned short h1 = f2bf(p1), l1 = f2bf(p1 - bf2f(h1));
            int rn = qd * 4 + r;
            pH[w][rn][ll] = h0;  pH[w][rn][16 + ll] = h1;
            pL[w][rn][ll] = l0;  pL[w][rn][16 + ll] = l1;
        }
        if (ll == 0) {
            #pragma unroll
            for (int r = 0; r < 4; ++r) alphaS[w][qd * 4 + r] = alpha4[r];
        }
        __builtin_amdgcn_wave_barrier();   // intra-wave LDS RAW (per-wave slab)
        short8 bph = *(const short8*)&pH[w][ll][qd * 8];
        short8 bpl = *(const short8*)&pL[w][ll][qd * 8];
        float an = alphaS[w][ll];
        // l accumulation: D2[i][j] = sum_k P[k][j]  (A = ones matrix)
        {
            f32x4 o = lacc;
            o[0] *= an; o[1] *= an; o[2] *= an; o[3] *= an;
            o = __builtin_amdgcn_mfma_f32_16x16x32_bf16(ones, bph, o, 0, 0, 0);
            o = __builtin_amdgcn_mfma_f32_16x16x32_bf16(ones, bpl, o, 0, 0, 0);
            lacc = o;
        }
        const unsigned short* vp0 = vbh + m0;
        const unsigned short* vp1 = vbl + m0;
        #pragma unroll
        for (int ct = 0; ct < 16; ++ct) {
            short8 avh = *(const short8*)(vp0 + (size_t)ct * 16 * M_);
            short8 avl = *(const short8*)(vp1 + (size_t)ct * 16 * M_);
            f32x4 o = oacc[ct];
            o[0] *= an; o[1] *= an; o[2] *= an; o[3] *= an;
            o = __builtin_amdgcn_mfma_f32_16x16x32_bf16(avh, bph, o, 0, 0, 0);
            o = __builtin_amdgcn_mfma_f32_16x16x32_bf16(avl, bph, o, 0, 0, 0);
            o = __builtin_amdgcn_mfma_f32_16x16x32_bf16(avh, bpl, o, 0, 0, 0);
            oacc[ct] = o;
        }
        __builtin_amdgcn_wave_barrier();   // WAR before next iter's P writes
    }

    // Merge the two m-halves (exact online-softmax algebra) and write out.
    // lacc[r] (any r) = this half's row-sum l for q-row ll, already lane-aligned.
    if (ll == 0) {
        #pragma unroll
        for (int r = 0; r < 4; ++r) mS[w][qd * 4 + r] = mrun[r];
    }
    if (mhalf == 1 && qd == 0) lS[wq][ll] = lacc[0];
    __syncthreads();
    float f0 = 0.f, f1 = 0.f;
    if (mhalf == 0) {
        float m0v = mS[wq][ll],  m1v = mS[2 + wq][ll];
        float l0v = lacc[0],     l1v = lS[wq][ll];
        float M = fmaxf(m0v, m1v);
        float a0 = __expf(m0v - M), a1 = __expf(m1v - M);
        float linv = 1.f / (l0v * a0 + l1v * a1);
        float g = gamma[0];
        f0 = a0 * linv * g;
        f1 = a1 * linv * g;
    }
    float* ob = out + (size_t)bat * C_ * N_ + n0 + ll;
    for (int cc = 0; cc < 4; ++cc) {
        if (mhalf == 1) {
            #pragma unroll
            for (int ctl = 0; ctl < 4; ++ctl) {
                int ct = cc * 4 + ctl;
                #pragma unroll
                for (int r = 0; r < 4; ++r)
                    oS[wq][ctl][qd * 4 + r][ll] = oacc[ct][r];
            }
        }
        __syncthreads();
        if (mhalf == 0) {
            #pragma unroll
            for (int ctl = 0; ctl < 4; ++ctl) {
                int ct = cc * 4 + ctl;
                #pragma unroll
                for (int r = 0; r < 4; ++r) {
                    int c = ct * 16 + qd * 4 + r;
                    float mrg = oacc[ct][r] * f0 + oS[wq][ctl][qd * 4 + r][ll] * f1;
                    ob[(size_t)c * N_] = mrg;
                }
            }
        }
        __syncthreads();
    }
}

// ---------------------------------------------------------------------------
extern "C" void kernel_launch(void* const* d_in, const int* in_sizes, int n_in,
                              void* d_out, int out_size, void* d_ws, size_t ws_size,
                              hipStream_t stream)
{
    const float* x   = (const float*)d_in[0];
    const float* y   = (const float*)d_in[1];
    const float* Wq  = (const float*)d_in[2];
    const float* bq  = (const float*)d_in[3];
    const float* gqs = (const float*)d_in[4];
    const float* gqb = (const float*)d_in[5];
    const float* Wk  = (const float*)d_in[6];
    const float* bk  = (const float*)d_in[7];
    const float* gks = (const float*)d_in[8];
    const float* gkb = (const float*)d_in[9];
    const float* Wv  = (const float*)d_in[10];
    const float* bv  = (const float*)d_in[11];
    const float* gvs = (const float*)d_in[12];
    const float* gvb = (const float*)d_in[13];
    const float* gamma = (const float*)d_in[14];
    float* out = (float*)d_out;

    // ws layout (71.6 MB total, all phases):
    //   qH, qL: 2 x 16.78 MB
    //   regA (phase-overlaid, 38.05 MB):
    //     conv3 phase:  xpH,xpL [8][66][66][256] bf16 + wtH,wtL       (38.05 MB)
    //     conv2 phase:  kf,vf fp32 (16.78) | yT half-batch (16.78) | w2 (2.10)
    //     gn/attn:      kf,vf | kTh,kTl,vH,vL | stats                 (33.57 MB)
    char* base = (char*)d_ws;
    unsigned short* qH = (unsigned short*)base;
    unsigned short* qL = qH + 8388608;
    char* regA = (char*)(qL + 8388608);
    // conv3 overlay
    unsigned short* xpH = (unsigned short*)regA;      // 8,921,088 shorts
    unsigned short* xpL = xpH + 8921088;
    unsigned short* wtH = xpL + 8921088;              // 589,824 shorts
    unsigned short* wtL = wtH + 589824;
    // pipeline overlay
    float* kf = (float*)regA;                         // 2,097,152 floats
    float* vf = kf + 2097152;
    unsigned short* kTh = (unsigned short*)(vf + 2097152);
    unsigned short* kTl = kTh + 2097152;
    unsigned short* vH  = kTl + 2097152;
    unsigned short* vL  = vH + 2097152;
    float* stq = (float*)(vL + 2097152);
    float* stk = stq + 512;
    float* stv = stk + 512;
    // conv2 overlay (after kf,vf; dead once conv2x2_mfma finishes)
    unsigned short* yTh  = (unsigned short*)(vf + 2097152);   // 4,194,304 shorts (4 bat)
    unsigned short* yTl  = yTh + 4194304;
    unsigned short* w2kH = yTl + 4194304;                     // 262,144 shorts each
    unsigned short* w2kL = w2kH + 262144;
    unsigned short* w2vH = w2kL + 262144;
    unsigned short* w2vL = w2vH + 262144;

    // conv3x3 (q path) via MFMA
    hipMemsetAsync(xpH, 0, (size_t)2 * 8921088 * sizeof(unsigned short), stream);
    split_w_tap<<<256, 256, 0, stream>>>(Wq, wtH, wtL);
    split_x_pad<<<512, 256, 0, stream>>>(x, xpH, xpL);
    conv3x3_mfma<<<512, 256, 0, stream>>>(xpH, xpL, wtH, wtL, bq, qH, qL);

    // conv2x2 (k,v) via MFMA, two 4-batch halves (fits 71.6 MB workspace).
    split_w2<<<256, 256, 0, stream>>>(Wk, w2kH, w2kL);
    split_w2<<<256, 256, 0, stream>>>(Wv, w2vH, w2vL);
    split_y_t<<<256, 256, 0, stream>>>(y, yTh, yTl, 0);
    conv2x2_mfma<<<128, 256, 0, stream>>>(yTh, yTl, w2kH, w2kL, w2vH, w2vL,
                                          bk, bv, kf, vf, 0);
    split_y_t<<<256, 256, 0, stream>>>(y, yTh, yTl, 4);
    conv2x2_mfma<<<128, 256, 0, stream>>>(yTh, yTl, w2kH, w2kL, w2vH, w2vL,
                                          bk, bv, kf, vf, 4);

    gn_stats_pair<<<256, 256, 0, stream>>>(qH, qL, stq, 4096);
    gn_stats_kernel<<<256, 256, 0, stream>>>(kf, stk, 1024);
    gn_stats_kernel<<<256, 256, 0, stream>>>(vf, stv, 1024);
    gn_silu_pair<<<4096, 256, 0, stream>>>(qH, qL, stq, gqs, gqb, 0.0625f, 1048576);
    gn_silu_split_v<<<1024, 256, 0, stream>>>(vf, vH, vL, stv, gvs, gvb, 262144);
    gn_silu_split_kT<<<1024, 256, 0, stream>>>(kf, kTh, kTl, stk, gks, gkb);
    attn_mfma<<<1024, 256, 0, stream>>>(qH, qL, kTh, kTl, vH, vL, gamma, out);
}

// Round 5
// 1056.564 us; speedup vs baseline: 1.1525x; 1.1525x over previous
//
#include <hip/hip_runtime.h>
#include <hip/hip_bf16.h>
#include <math.h>

#define B_ 8
#define C_ 256
#define H_ 64
#define W_ 64
#define N_ 4096
#define M_ 1024
#define HW_ 4096

typedef __attribute__((ext_vector_type(8))) short short8;
typedef __attribute__((ext_vector_type(4))) float f32x4;

__device__ __forceinline__ unsigned short f2bf(float x) {
    unsigned u = __float_as_uint(x);
    u += 0x7fffu + ((u >> 16) & 1u);          // round-to-nearest-even
    return (unsigned short)(u >> 16);
}
__device__ __forceinline__ float bf2f(unsigned short h) {
    return __uint_as_float(((unsigned)h) << 16);
}

// ---------------------------------------------------------------------------
// Split Wq [256co][256ci][3][3] fp32 -> per-tap bf16 hi/lo [9][256co][256ci].
__global__ __launch_bounds__(256) void split_w_tap(
    const float* __restrict__ Wq, unsigned short* __restrict__ wtH,
    unsigned short* __restrict__ wtL)
{
    int co = blockIdx.x, ci = threadIdx.x;
    const float* wp = Wq + ((size_t)co * 256 + ci) * 9;
    #pragma unroll
    for (int tap = 0; tap < 9; ++tap) {
        float v = wp[tap];
        unsigned short h = f2bf(v), l = f2bf(v - bf2f(h));
        size_t o = ((size_t)tap << 16) + ((size_t)co << 8) + ci;
        wtH[o] = h; wtL[o] = l;
    }
}

// Split W [256co][256ci][2][2] fp32 -> per-tap bf16 hi/lo [4][256co][256ci].
__global__ __launch_bounds__(256) void split_w2(
    const float* __restrict__ Wsrc, unsigned short* __restrict__ wH,
    unsigned short* __restrict__ wL)
{
    int co = blockIdx.x, ci = threadIdx.x;
    const float* wp = Wsrc + ((size_t)co * 256 + ci) * 4;
    #pragma unroll
    for (int tap = 0; tap < 4; ++tap) {
        float v = wp[tap];
        unsigned short h = f2bf(v), l = f2bf(v - bf2f(h));
        size_t o = ((size_t)tap << 16) + ((size_t)co << 8) + ci;
        wH[o] = h; wL[o] = l;
    }
}

// ---------------------------------------------------------------------------
// Transpose+split x [8][256][64][64] fp32 -> padded NHWC bf16 hi/lo
// [8][66][66][256] (halo pre-zeroed by memset). LDS-tiled transpose.
__global__ __launch_bounds__(256) void split_x_pad(
    const float* __restrict__ x, unsigned short* __restrict__ xpH,
    unsigned short* __restrict__ xpL)
{
    __shared__ float tile[64][65];
    int blk = blockIdx.x;            // b*64 + h
    int b = blk >> 6, h = blk & 63;
    int t = threadIdx.x;
    const float* xb = x + ((size_t)b << 20) + (size_t)h * 64;
    size_t obase = (((size_t)b * 4356) + (size_t)(h + 1) * 66 + 1) * 256;
    unsigned short* oH = xpH + obase;
    unsigned short* oL = xpL + obase;
    for (int cc = 0; cc < 256; cc += 64) {
        int wi = t & 63, cq = t >> 6;
        #pragma unroll
        for (int r = 0; r < 16; ++r) {
            int cl = cq * 16 + r;
            tile[cl][wi] = xb[((size_t)(cc + cl)) * 4096 + wi];
        }
        __syncthreads();
        int cl = t & 63, wq = t >> 6;
        #pragma unroll
        for (int r = 0; r < 16; ++r) {
            int wwi = wq * 16 + r;
            float v = tile[cl][wwi];
            unsigned short hh = f2bf(v), lo = f2bf(v - bf2f(hh));
            size_t o = (size_t)wwi * 256 + cc + cl;
            oH[o] = hh; oL[o] = lo;
        }
        __syncthreads();
    }
}

// Transpose+split y (4-batch half) fp32 -> NHWC bf16 hi/lo [4][64][64][256].
__global__ __launch_bounds__(256) void split_y_t(
    const float* __restrict__ y, unsigned short* __restrict__ yTh,
    unsigned short* __restrict__ yTl, int b0)
{
    __shared__ float tile[64][65];
    int blk = blockIdx.x;            // bl*64 + h, bl in [0,4)
    int bl = blk >> 6, h = blk & 63;
    int t = threadIdx.x;
    const float* yb = y + ((size_t)(b0 + bl) << 20) + (size_t)h * 64;
    size_t obase = (((size_t)bl << 12) + (size_t)h * 64) * 256;
    unsigned short* oH = yTh + obase;
    unsigned short* oL = yTl + obase;
    for (int cc = 0; cc < 256; cc += 64) {
        int wi = t & 63, cq = t >> 6;
        #pragma unroll
        for (int r = 0; r < 16; ++r) {
            int cl = cq * 16 + r;
            tile[cl][wi] = yb[((size_t)(cc + cl)) * 4096 + wi];
        }
        __syncthreads();
        int cl = t & 63, wq = t >> 6;
        #pragma unroll
        for (int r = 0; r < 16; ++r) {
            int wwi = wq * 16 + r;
            float v = tile[cl][wwi];
            unsigned short hh = f2bf(v), lo = f2bf(v - bf2f(hh));
            size_t o = (size_t)wwi * 256 + cc + cl;
            oH[o] = hh; oL[o] = lo;
        }
        __syncthreads();
    }
}

// ---------------------------------------------------------------------------
// conv 3x3 s1 p1 via MFMA: per-tap GEMM sum, split-bf16 3-term fp32 emulation.
__global__ __launch_bounds__(256, 2) void conv3x3_mfma(
    const unsigned short* __restrict__ xpH, const unsigned short* __restrict__ xpL,
    const unsigned short* __restrict__ wtH, const unsigned short* __restrict__ wtL,
    const float* __restrict__ bq,
    unsigned short* __restrict__ qH, unsigned short* __restrict__ qL)
{
    int blk = blockIdx.x;
    int bat = blk & 7;
    int rest = blk >> 3;
    int cot = rest & 1;
    int pxt = rest >> 1;                  // 32 tiles of 128 px (2 rows of 64)
    int t = threadIdx.x;
    int wv = t >> 6;
    int wco = wv >> 1, wpx = wv & 1;
    int lane = t & 63;
    int ll = lane & 15, qd = lane >> 4;

    const int co0 = cot * 128 + wco * 64;
    const unsigned short* aHp[4]; const unsigned short* aLp[4];
    #pragma unroll
    for (int ib = 0; ib < 4; ++ib) {
        size_t o = ((size_t)(co0 + ib * 16 + ll)) * 256 + qd * 8;
        aHp[ib] = wtH + o; aLp[ib] = wtL + o;
    }
    const unsigned short* bHp[4]; const unsigned short* bLp[4];
    const int h0 = pxt * 2;
    #pragma unroll
    for (int jb = 0; jb < 4; ++jb) {
        int pxl = wpx * 64 + jb * 16 + ll;
        int hh = h0 + (pxl >> 6);
        int ww = pxl & 63;
        size_t o = ((size_t)bat * 4356 + (size_t)hh * 66 + ww) * 256 + qd * 8;
        bHp[jb] = xpH + o; bLp[jb] = xpL + o;
    }

    f32x4 acc[4][4];
    #pragma unroll
    for (int i = 0; i < 4; ++i)
        #pragma unroll
        for (int j = 0; j < 4; ++j) acc[i][j] = (f32x4){0.f, 0.f, 0.f, 0.f};

    int boff = 0;   // (kh*66+kw)*256 shorts
    int kw = 0;
    for (int tap = 0; tap < 9; ++tap) {
        const int aoff = tap << 16;
        #pragma unroll 2
        for (int ci0 = 0; ci0 < 256; ci0 += 32) {
            short8 avh[4], avl[4], bvh[4], bvl[4];
            #pragma unroll
            for (int ib = 0; ib < 4; ++ib) {
                avh[ib] = *(const short8*)(aHp[ib] + aoff + ci0);
                avl[ib] = *(const short8*)(aLp[ib] + aoff + ci0);
            }
            #pragma unroll
            for (int jb = 0; jb < 4; ++jb) {
                bvh[jb] = *(const short8*)(bHp[jb] + boff + ci0);
                bvl[jb] = *(const short8*)(bLp[jb] + boff + ci0);
            }
            #pragma unroll
            for (int ib = 0; ib < 4; ++ib)
                #pragma unroll
                for (int jb = 0; jb < 4; ++jb) {
                    f32x4 o = acc[ib][jb];
                    o = __builtin_amdgcn_mfma_f32_16x16x32_bf16(avh[ib], bvh[jb], o, 0, 0, 0);
                    o = __builtin_amdgcn_mfma_f32_16x16x32_bf16(avl[ib], bvh[jb], o, 0, 0, 0);
                    o = __builtin_amdgcn_mfma_f32_16x16x32_bf16(avh[ib], bvl[jb], o, 0, 0, 0);
                    acc[ib][jb] = o;
                }
        }
        kw++;
        boff += 256;
        if (kw == 3) { kw = 0; boff += 63 * 256; }
    }

    const int pxbase = pxt * 128 + wpx * 64;
    #pragma unroll
    for (int ib = 0; ib < 4; ++ib) {
        #pragma unroll
        for (int r = 0; r < 4; ++r) {
            int co = co0 + ib * 16 + qd * 4 + r;
            float bvv = bq[co];
            size_t rowo = ((size_t)(bat * 256 + co)) << 12;
            #pragma unroll
            for (int jb = 0; jb < 4; ++jb) {
                float v = acc[ib][jb][r] + bvv;
                unsigned short h = f2bf(v), l = f2bf(v - bf2f(h));
                size_t o = rowo + pxbase + jb * 16 + ll;
                qH[o] = h; qL[o] = l;
            }
        }
    }
}

// ---------------------------------------------------------------------------
// conv 2x2 s2 p0 via MFMA (k and v), 4-batch half. Grid 128 = 4 bat x 4 sel
// x 8 m-tiles. Block 256 = 4 waves (2co x 2m). fp32 out (pre-GN).
__global__ __launch_bounds__(256, 2) void conv2x2_mfma(
    const unsigned short* __restrict__ yTh, const unsigned short* __restrict__ yTl,
    const unsigned short* __restrict__ wkH, const unsigned short* __restrict__ wkL,
    const unsigned short* __restrict__ wvH, const unsigned short* __restrict__ wvL,
    const float* __restrict__ bk, const float* __restrict__ bv,
    float* __restrict__ kf, float* __restrict__ vf, int b0)
{
    int blk = blockIdx.x;
    int batl = blk & 3;
    int sel = (blk >> 2) & 3;
    int mt  = blk >> 4;                   // 0..7, 128 m each
    int t = threadIdx.x;
    int wv_ = t >> 6;
    int wco = wv_ >> 1, wpx = wv_ & 1;
    int lane = t & 63;
    int ll = lane & 15, qd = lane >> 4;

    const unsigned short* wtH_; const unsigned short* wtL_;
    const float* bias; float* dst; int co0;
    if (sel < 2) { wtH_ = wkH; wtL_ = wkL; bias = bk; dst = kf; co0 = sel * 128 + wco * 64; }
    else         { wtH_ = wvH; wtL_ = wvL; bias = bv; dst = vf; co0 = (sel - 2) * 128 + wco * 64; }

    const unsigned short* aHp[4]; const unsigned short* aLp[4];
    #pragma unroll
    for (int ib = 0; ib < 4; ++ib) {
        size_t o = ((size_t)(co0 + ib * 16 + ll)) * 256 + qd * 8;
        aHp[ib] = wtH_ + o; aLp[ib] = wtL_ + o;
    }
    const unsigned short* bHp[4]; const unsigned short* bLp[4];
    #pragma unroll
    for (int jb = 0; jb < 4; ++jb) {
        int m = mt * 128 + wpx * 64 + jb * 16 + ll;
        int mh = m >> 5, mw = m & 31;
        size_t o = (((size_t)batl << 12) + (size_t)(2 * mh) * 64 + 2 * mw) * 256 + qd * 8;
        bHp[jb] = yTh + o; bLp[jb] = yTl + o;
    }

    f32x4 acc[4][4];
    #pragma unroll
    for (int i = 0; i < 4; ++i)
        #pragma unroll
        for (int j = 0; j < 4; ++j) acc[i][j] = (f32x4){0.f, 0.f, 0.f, 0.f};

    #pragma unroll
    for (int tap = 0; tap < 4; ++tap) {
        const int aoff = tap << 16;
        const int boff = (((tap >> 1) * 64) + (tap & 1)) * 256;
        #pragma unroll 2
        for (int ci0 = 0; ci0 < 256; ci0 += 32) {
            short8 avh[4], avl[4], bvh[4], bvl[4];
            #pragma unroll
            for (int ib = 0; ib < 4; ++ib) {
                avh[ib] = *(const short8*)(aHp[ib] + aoff + ci0);
                avl[ib] = *(const short8*)(aLp[ib] + aoff + ci0);
            }
            #pragma unroll
            for (int jb = 0; jb < 4; ++jb) {
                bvh[jb] = *(const short8*)(bHp[jb] + boff + ci0);
                bvl[jb] = *(const short8*)(bLp[jb] + boff + ci0);
            }
            #pragma unroll
            for (int ib = 0; ib < 4; ++ib)
                #pragma unroll
                for (int jb = 0; jb < 4; ++jb) {
                    f32x4 o = acc[ib][jb];
                    o = __builtin_amdgcn_mfma_f32_16x16x32_bf16(avh[ib], bvh[jb], o, 0, 0, 0);
                    o = __builtin_amdgcn_mfma_f32_16x16x32_bf16(avl[ib], bvh[jb], o, 0, 0, 0);
                    o = __builtin_amdgcn_mfma_f32_16x16x32_bf16(avh[ib], bvl[jb], o, 0, 0, 0);
                    acc[ib][jb] = o;
                }
        }
    }

    const int mbase = mt * 128 + wpx * 64;
    #pragma unroll
    for (int ib = 0; ib < 4; ++ib) {
        #pragma unroll
        for (int r = 0; r < 4; ++r) {
            int co = co0 + ib * 16 + qd * 4 + r;
            float bvv = bias[co];
            float* op = dst + (((size_t)((b0 + batl) * 256 + co)) << 10) + mbase + ll;
            #pragma unroll
            for (int jb = 0; jb < 4; ++jb)
                op[jb * 16] = acc[ib][jb][r] + bvv;
        }
    }
}

// ---------------------------------------------------------------------------
// GroupNorm stats (fp32 input): one block per (batch, group).
__global__ __launch_bounds__(256) void gn_stats_kernel(
    const float* __restrict__ buf, float* __restrict__ stats, int S)
{
    int bg = blockIdx.x;
    const float4* p = (const float4*)(buf + (size_t)bg * 8 * S);
    int n4 = 2 * S;
    float s = 0.f, s2 = 0.f;
    for (int i = threadIdx.x; i < n4; i += 256) {
        float4 vv = p[i];
        s  += vv.x + vv.y + vv.z + vv.w;
        s2 += vv.x * vv.x + vv.y * vv.y + vv.z * vv.z + vv.w * vv.w;
    }
    for (int d = 1; d < 64; d <<= 1) { s += __shfl_xor(s, d); s2 += __shfl_xor(s2, d); }
    __shared__ float red[8];
    int w = threadIdx.x >> 6;
    if ((threadIdx.x & 63) == 0) { red[w] = s; red[w + 4] = s2; }
    __syncthreads();
    if (threadIdx.x == 0) {
        s  = red[0] + red[1] + red[2] + red[3];
        s2 = red[4] + red[5] + red[6] + red[7];
        float invn = 1.f / (float)(8 * S);
        float mean = s * invn;
        float var = s2 * invn - mean * mean;
        if (var < 0.f) var = 0.f;
        stats[bg * 2]     = mean;
        stats[bg * 2 + 1] = 1.f / sqrtf(var + 1e-5f);
    }
}

// GroupNorm stats from bf16 hi/lo pair (q path).
__global__ __launch_bounds__(256) void gn_stats_pair(
    const unsigned short* __restrict__ hi, const unsigned short* __restrict__ lo,
    float* __restrict__ stats, int S)
{
    int bg = blockIdx.x;
    const uint4* ph = (const uint4*)(hi + (size_t)bg * 8 * S);
    const uint4* pl = (const uint4*)(lo + (size_t)bg * 8 * S);
    int n8 = S;
    float s = 0.f, s2 = 0.f;
    for (int i = threadIdx.x; i < n8; i += 256) {
        uint4 a = ph[i], b2 = pl[i];
        unsigned ua[4] = {a.x, a.y, a.z, a.w}, ub[4] = {b2.x, b2.y, b2.z, b2.w};
        #pragma unroll
        for (int j = 0; j < 4; ++j) {
            float x0 = __uint_as_float(ua[j] << 16) + __uint_as_float(ub[j] << 16);
            float x1 = __uint_as_float(ua[j] & 0xffff0000u) + __uint_as_float(ub[j] & 0xffff0000u);
            s += x0 + x1;
            s2 += x0 * x0 + x1 * x1;
        }
    }
    for (int d = 1; d < 64; d <<= 1) { s += __shfl_xor(s, d); s2 += __shfl_xor(s2, d); }
    __shared__ float red[8];
    int w = threadIdx.x >> 6;
    if ((threadIdx.x & 63) == 0) { red[w] = s; red[w + 4] = s2; }
    __syncthreads();
    if (threadIdx.x == 0) {
        s  = red[0] + red[1] + red[2] + red[3];
        s2 = red[4] + red[5] + red[6] + red[7];
        float invn = 1.f / (float)(8 * S);
        float mean = s * invn;
        float var = s2 * invn - mean * mean;
        if (var < 0.f) var = 0.f;
        stats[bg * 2]     = mean;
        stats[bg * 2 + 1] = 1.f / sqrtf(var + 1e-5f);
    }
}

// GN + affine + SiLU (+extra scale) on bf16 pair, in place (q path, N=4096).
__global__ __launch_bounds__(256) void gn_silu_pair(
    unsigned short* __restrict__ hi, unsigned short* __restrict__ lo,
    const float* __restrict__ stats, const float* __restrict__ scale,
    const float* __restrict__ bias, float extra, int total8)
{
    int idx = blockIdx.x * 256 + threadIdx.x;
    if (idx >= total8) return;
    size_t e = (size_t)idx * 8;
    int c  = (int)((e >> 12) & 255);
    int gg = (int)(e >> 15);
    float mean = stats[gg * 2], rstd = stats[gg * 2 + 1];
    float a  = scale[c] * rstd;
    float bb = bias[c] - mean * a;
    uint4 uh = ((uint4*)hi)[idx], ul = ((uint4*)lo)[idx];
    unsigned ha[4] = {uh.x, uh.y, uh.z, uh.w}, la[4] = {ul.x, ul.y, ul.z, ul.w};
    unsigned oh[4], ol[4];
    #pragma unroll
    for (int j = 0; j < 4; ++j) {
        float x0 = __uint_as_float(ha[j] << 16) + __uint_as_float(la[j] << 16);
        float x1 = __uint_as_float(ha[j] & 0xffff0000u) + __uint_as_float(la[j] & 0xffff0000u);
        float y0 = x0 * a + bb, y1 = x1 * a + bb;
        float s0 = extra * y0 / (1.f + __expf(-y0));
        float s1 = extra * y1 / (1.f + __expf(-y1));
        unsigned short h0 = f2bf(s0), l0 = f2bf(s0 - bf2f(h0));
        unsigned short h1 = f2bf(s1), l1 = f2bf(s1 - bf2f(h1));
        oh[j] = h0 | ((unsigned)h1 << 16);
        ol[j] = l0 | ((unsigned)l1 << 16);
    }
    ((uint4*)hi)[idx] = make_uint4(oh[0], oh[1], oh[2], oh[3]);
    ((uint4*)lo)[idx] = make_uint4(ol[0], ol[1], ol[2], ol[3]);
}

// GN + affine + SiLU on fp32 v -> bf16 hi/lo pair, natural [C][M] layout.
__global__ __launch_bounds__(256) void gn_silu_split_v(
    const float* __restrict__ vf, unsigned short* __restrict__ hi,
    unsigned short* __restrict__ lo, const float* __restrict__ stats,
    const float* __restrict__ scale, const float* __restrict__ bias, int total8)
{
    int idx = blockIdx.x * 256 + threadIdx.x;
    if (idx >= total8) return;
    size_t e = (size_t)idx * 8;
    int c  = (int)((e >> 10) & 255);
    int gg = (int)(e >> 13);
    float mean = stats[gg * 2], rstd = stats[gg * 2 + 1];
    float a  = scale[c] * rstd;
    float bb = bias[c] - mean * a;
    float4 f0 = ((const float4*)vf)[idx * 2];
    float4 f1 = ((const float4*)vf)[idx * 2 + 1];
    float xs[8] = {f0.x, f0.y, f0.z, f0.w, f1.x, f1.y, f1.z, f1.w};
    unsigned oh[4], ol[4];
    #pragma unroll
    for (int j = 0; j < 4; ++j) {
        float y0 = xs[2 * j] * a + bb, y1 = xs[2 * j + 1] * a + bb;
        float s0 = y0 / (1.f + __expf(-y0));
        float s1 = y1 / (1.f + __expf(-y1));
        unsigned short h0 = f2bf(s0), l0 = f2bf(s0 - bf2f(h0));
        unsigned short h1 = f2bf(s1), l1 = f2bf(s1 - bf2f(h1));
        oh[j] = h0 | ((unsigned)h1 << 16);
        ol[j] = l0 | ((unsigned)l1 << 16);
    }
    ((uint4*)hi)[idx] = make_uint4(oh[0], oh[1], oh[2], oh[3]);
    ((uint4*)lo)[idx] = make_uint4(ol[0], ol[1], ol[2], ol[3]);
}

// GN + affine + SiLU on fp32 k -> TRANSPOSED bf16 hi/lo [B][M][C] (B-frag layout).
__global__ __launch_bounds__(256) void gn_silu_split_kT(
    const float* __restrict__ kf, unsigned short* __restrict__ th,
    unsigned short* __restrict__ tl, const float* __restrict__ stats,
    const float* __restrict__ scale, const float* __restrict__ bias)
{
    int bm = blockIdx.x;              // 8 batches * 128 m8-groups
    int b = bm >> 7, m8 = (bm & 127) * 8;
    int c = threadIdx.x;
    int gg = b * 32 + (c >> 3);
    float mean = stats[gg * 2], rstd = stats[gg * 2 + 1];
    float a  = scale[c] * rstd;
    float bb = bias[c] - mean * a;
    const float* src = kf + (((size_t)(b * 256 + c)) << 10) + m8;
    float4 f0 = *(const float4*)src;
    float4 f1 = *(const float4*)(src + 4);
    float xs[8] = {f0.x, f0.y, f0.z, f0.w, f1.x, f1.y, f1.z, f1.w};
    #pragma unroll
    for (int j = 0; j < 8; ++j) {
        float y = xs[j] * a + bb;
        float s = y / (1.f + __expf(-y));
        unsigned short h = f2bf(s), l = f2bf(s - bf2f(h));
        size_t o = ((size_t)b * M_ + m8 + j) * C_ + c;
        th[o] = h;
        tl[o] = l;
    }
}

// ---------------------------------------------------------------------------
// Fused flash attention, split-bf16 MFMA (3-term fp32 emulation).
// Grid 1024 = 8 bat x 128 n-tiles (32 q-rows). Block 256 = 4 waves:
// 2 q-waves x 2 m-half waves; in-LDS merge. 64-m SUPER-TILES per iteration:
// QK runs 4 independent MFMA chains (ILP for the 2-wave/SIMD regime), one
// online-softmax rescale per 64 m (half the shfl/rescale/barrier cost).
// launch_bounds(256,2): natural ~140V+68A allocation, NO spills (R4 lesson).
__global__ __launch_bounds__(256, 2) void attn_mfma(
    const unsigned short* __restrict__ qh, const unsigned short* __restrict__ qlo,
    const unsigned short* __restrict__ kth, const unsigned short* __restrict__ ktl,
    const unsigned short* __restrict__ vh, const unsigned short* __restrict__ vlo,
    const float* __restrict__ gamma, float* __restrict__ out)
{
    __shared__ __align__(16) unsigned short pH[4][16][72];
    __shared__ __align__(16) unsigned short pL[4][16][72];
    __shared__ float alphaS[4][16];
    __shared__ float mS[4][16];
    __shared__ float lS[2][16];
    __shared__ __align__(16) float oS[2][4][16][17];   // [wq][ctl][c-row][n-col]

    int blk = blockIdx.x;
    int bat = blk & 7;
    int nt  = blk >> 3;           // 0..127
    int t = threadIdx.x;
    int w = t >> 6;               // 0..3
    int wq = w & 1;
    int mhalf = w >> 1;
    int lane = t & 63;
    int ll = lane & 15;
    int qd = lane >> 4;
    int n0 = nt * 32 + wq * 16;

    short8 aqh[8], aql[8];
    {
        const unsigned short* qb1 = qh  + (size_t)bat * C_ * N_ + n0 + ll;
        const unsigned short* qb2 = qlo + (size_t)bat * C_ * N_ + n0 + ll;
        #pragma unroll
        for (int ks = 0; ks < 8; ++ks) {
            #pragma unroll
            for (int j = 0; j < 8; ++j) {
                size_t off = (size_t)(ks * 32 + qd * 8 + j) * N_;
                aqh[ks][j] = (short)qb1[off];
                aql[ks][j] = (short)qb2[off];
            }
        }
    }

    f32x4 oacc[16];
    #pragma unroll
    for (int i = 0; i < 16; ++i) oacc[i] = (f32x4){0.f, 0.f, 0.f, 0.f};
    f32x4 lacc = (f32x4){0.f, 0.f, 0.f, 0.f};
    float mrun[4] = {-3e38f, -3e38f, -3e38f, -3e38f};
    const short8 ones = (short8){16256, 16256, 16256, 16256, 16256, 16256, 16256, 16256};

    const unsigned short* ktbh = kth + (size_t)bat * M_ * C_ + (size_t)ll * C_ + qd * 8;
    const unsigned short* ktbl = ktl + (size_t)bat * M_ * C_ + (size_t)ll * C_ + qd * 8;
    const unsigned short* vbh  = vh  + (size_t)bat * C_ * M_ + (size_t)ll * M_ + qd * 8;
    const unsigned short* vbl  = vlo + (size_t)bat * C_ * M_ + (size_t)ll * M_ + qd * 8;

    for (int st = 0; st < 8; ++st) {
        int m0 = (mhalf * 8 + st) * 64;
        f32x4 s0 = {0.f, 0.f, 0.f, 0.f}, s1 = {0.f, 0.f, 0.f, 0.f};
        f32x4 s2 = {0.f, 0.f, 0.f, 0.f}, s3 = {0.f, 0.f, 0.f, 0.f};
        const unsigned short* k0h = ktbh + (size_t)m0 * C_;
        const unsigned short* k0l = ktbl + (size_t)m0 * C_;
        #pragma unroll
        for (int ks = 0; ks < 8; ++ks) {
            short8 b0h = *(const short8*)(k0h + ks * 32);
            short8 b1h = *(const short8*)(k0h + 16 * C_ + ks * 32);
            short8 b2h = *(const short8*)(k0h + 32 * C_ + ks * 32);
            short8 b3h = *(const short8*)(k0h + 48 * C_ + ks * 32);
            short8 b0l = *(const short8*)(k0l + ks * 32);
            short8 b1l = *(const short8*)(k0l + 16 * C_ + ks * 32);
            short8 b2l = *(const short8*)(k0l + 32 * C_ + ks * 32);
            short8 b3l = *(const short8*)(k0l + 48 * C_ + ks * 32);
            s0 = __builtin_amdgcn_mfma_f32_16x16x32_bf16(aqh[ks], b0h, s0, 0, 0, 0);
            s1 = __builtin_amdgcn_mfma_f32_16x16x32_bf16(aqh[ks], b1h, s1, 0, 0, 0);
            s2 = __builtin_amdgcn_mfma_f32_16x16x32_bf16(aqh[ks], b2h, s2, 0, 0, 0);
            s3 = __builtin_amdgcn_mfma_f32_16x16x32_bf16(aqh[ks], b3h, s3, 0, 0, 0);
            s0 = __builtin_amdgcn_mfma_f32_16x16x32_bf16(aql[ks], b0h, s0, 0, 0, 0);
            s1 = __builtin_amdgcn_mfma_f32_16x16x32_bf16(aql[ks], b1h, s1, 0, 0, 0);
            s2 = __builtin_amdgcn_mfma_f32_16x16x32_bf16(aql[ks], b2h, s2, 0, 0, 0);
            s3 = __builtin_amdgcn_mfma_f32_16x16x32_bf16(aql[ks], b3h, s3, 0, 0, 0);
            s0 = __builtin_amdgcn_mfma_f32_16x16x32_bf16(aqh[ks], b0l, s0, 0, 0, 0);
            s1 = __builtin_amdgcn_mfma_f32_16x16x32_bf16(aqh[ks], b1l, s1, 0, 0, 0);
            s2 = __builtin_amdgcn_mfma_f32_16x16x32_bf16(aqh[ks], b2l, s2, 0, 0, 0);
            s3 = __builtin_amdgcn_mfma_f32_16x16x32_bf16(aqh[ks], b3l, s3, 0, 0, 0);
        }
        // online softmax over 64-m super-tile: one rescale per iteration
        float alpha4[4];
        #pragma unroll
        for (int r = 0; r < 4; ++r) {
            float mx = fmaxf(fmaxf(s0[r], s1[r]), fmaxf(s2[r], s3[r]));
            mx = fmaxf(mx, __shfl_xor(mx, 1));
            mx = fmaxf(mx, __shfl_xor(mx, 2));
            mx = fmaxf(mx, __shfl_xor(mx, 4));
            mx = fmaxf(mx, __shfl_xor(mx, 8));
            float mn = fmaxf(mrun[r], mx);
            float al = __expf(mrun[r] - mn);
            mrun[r] = mn;
            float p0 = __expf(s0[r] - mn);
            float p1 = __expf(s1[r] - mn);
            float p2 = __expf(s2[r] - mn);
            float p3 = __expf(s3[r] - mn);
            alpha4[r] = al;
            unsigned short h0 = f2bf(p0), l0 = f2bf(p0 - bf2f(h0));
            unsigned short h1 = f2bf(p1), l1 = f2bf(p1 - bf2f(h1));
            unsigned short h2 = f2bf(p2), l2 = f2bf(p2 - bf2f(h2));
            unsigned short h3 = f2bf(p3), l3 = f2bf(p3 - bf2f(h3));
            int rn = qd * 4 + r;
            pH[w][rn][ll] = h0;  pH[w][rn][16 + ll] = h1;
            pH[w][rn][32 + ll] = h2;  pH[w][rn][48 + ll] = h3;
            pL[w][rn][ll] = l0;  pL[w][rn][16 + ll] = l1;
            pL[w][rn][32 + ll] = l2;  pL[w][rn][48 + ll] = l3;
        }
        if (ll == 0) {
            #pragma unroll
            for (int r = 0; r < 4; ++r) alphaS[w][qd * 4 + r] = alpha4[r];
        }
        __builtin_amdgcn_wave_barrier();   // intra-wave LDS RAW (per-wave slab)
        short8 bph0 = *(const short8*)&pH[w][ll][qd * 8];
        short8 bph1 = *(const short8*)&pH[w][ll][32 + qd * 8];
        short8 bpl0 = *(const short8*)&pL[w][ll][qd * 8];
        short8 bpl1 = *(const short8*)&pL[w][ll][32 + qd * 8];
        float an = alphaS[w][ll];
        // l accumulation via ones-MFMA (row-sum of P, lane-aligned by q-row)
        {
            f32x4 o = lacc;
            o[0] *= an; o[1] *= an; o[2] *= an; o[3] *= an;
            o = __builtin_amdgcn_mfma_f32_16x16x32_bf16(ones, bph0, o, 0, 0, 0);
            o = __builtin_amdgcn_mfma_f32_16x16x32_bf16(ones, bpl0, o, 0, 0, 0);
            o = __builtin_amdgcn_mfma_f32_16x16x32_bf16(ones, bph1, o, 0, 0, 0);
            o = __builtin_amdgcn_mfma_f32_16x16x32_bf16(ones, bpl1, o, 0, 0, 0);
            lacc = o;
        }
        const unsigned short* vp0 = vbh + m0;
        const unsigned short* vp1 = vbl + m0;
        #pragma unroll
        for (int ct = 0; ct < 16; ++ct) {
            short8 avh0 = *(const short8*)(vp0 + (size_t)ct * 16 * M_);
            short8 avl0 = *(const short8*)(vp1 + (size_t)ct * 16 * M_);
            short8 avh1 = *(const short8*)(vp0 + (size_t)ct * 16 * M_ + 32);
            short8 avl1 = *(const short8*)(vp1 + (size_t)ct * 16 * M_ + 32);
            f32x4 o = oacc[ct];
            o[0] *= an; o[1] *= an; o[2] *= an; o[3] *= an;
            o = __builtin_amdgcn_mfma_f32_16x16x32_bf16(avh0, bph0, o, 0, 0, 0);
            o = __builtin_amdgcn_mfma_f32_16x16x32_bf16(avl0, bph0, o, 0, 0, 0);
            o = __builtin_amdgcn_mfma_f32_16x16x32_bf16(avh0, bpl0, o, 0, 0, 0);
            o = __builtin_amdgcn_mfma_f32_16x16x32_bf16(avh1, bph1, o, 0, 0, 0);
            o = __builtin_amdgcn_mfma_f32_16x16x32_bf16(avl1, bph1, o, 0, 0, 0);
            o = __builtin_amdgcn_mfma_f32_16x16x32_bf16(avh1, bpl1, o, 0, 0, 0);
            oacc[ct] = o;
        }
        __builtin_amdgcn_wave_barrier();   // WAR before next iter's P writes
    }

    // Merge the two m-halves (exact online-softmax algebra) and write out.
    if (ll == 0) {
        #pragma unroll
        for (int r = 0; r < 4; ++r) mS[w][qd * 4 + r] = mrun[r];
    }
    if (mhalf == 1 && qd == 0) lS[wq][ll] = lacc[0];
    __syncthreads();
    float f0 = 0.f, f1 = 0.f;
    if (mhalf == 0) {
        float m0v = mS[wq][ll],  m1v = mS[2 + wq][ll];
        float l0v = lacc[0],     l1v = lS[wq][ll];
        float M = fmaxf(m0v, m1v);
        float a0 = __expf(m0v - M), a1 = __expf(m1v - M);
        float linv = 1.f / (l0v * a0 + l1v * a1);
        float g = gamma[0];
        f0 = a0 * linv * g;
        f1 = a1 * linv * g;
    }
    float* ob = out + (size_t)bat * C_ * N_ + n0 + ll;
    for (int cc = 0; cc < 4; ++cc) {
        if (mhalf == 1) {
            #pragma unroll
            for (int ctl = 0; ctl < 4; ++ctl) {
                int ct = cc * 4 + ctl;
                #pragma unroll
                for (int r = 0; r < 4; ++r)
                    oS[wq][ctl][qd * 4 + r][ll] = oacc[ct][r];
            }
        }
        __syncthreads();
        if (mhalf == 0) {
            #pragma unroll
            for (int ctl = 0; ctl < 4; ++ctl) {
                int ct = cc * 4 + ctl;
                #pragma unroll
                for (int r = 0; r < 4; ++r) {
                    int c = ct * 16 + qd * 4 + r;
                    float mrg = oacc[ct][r] * f0 + oS[wq][ctl][qd * 4 + r][ll] * f1;
                    ob[(size_t)c * N_] = mrg;
                }
            }
        }
        __syncthreads();
    }
}

// ---------------------------------------------------------------------------
extern "C" void kernel_launch(void* const* d_in, const int* in_sizes, int n_in,
                              void* d_out, int out_size, void* d_ws, size_t ws_size,
                              hipStream_t stream)
{
    const float* x   = (const float*)d_in[0];
    const float* y   = (const float*)d_in[1];
    const float* Wq  = (const float*)d_in[2];
    const float* bq  = (const float*)d_in[3];
    const float* gqs = (const float*)d_in[4];
    const float* gqb = (const float*)d_in[5];
    const float* Wk  = (const float*)d_in[6];
    const float* bk  = (const float*)d_in[7];
    const float* gks = (const float*)d_in[8];
    const float* gkb = (const float*)d_in[9];
    const float* Wv  = (const float*)d_in[10];
    const float* bv  = (const float*)d_in[11];
    const float* gvs = (const float*)d_in[12];
    const float* gvb = (const float*)d_in[13];
    const float* gamma = (const float*)d_in[14];
    float* out = (float*)d_out;

    // ws layout (71.6 MB total, all phases):
    //   qH, qL: 2 x 16.78 MB
    //   regA (phase-overlaid, 38.05 MB):
    //     conv3 phase:  xpH,xpL [8][66][66][256] bf16 + wtH,wtL       (38.05 MB)
    //     conv2 phase:  kf,vf fp32 (16.78) | yT half-batch (16.78) | w2 (2.10)
    //     gn/attn:      kf,vf | kTh,kTl,vH,vL | stats                 (33.57 MB)
    char* base = (char*)d_ws;
    unsigned short* qH = (unsigned short*)base;
    unsigned short* qL = qH + 8388608;
    char* regA = (char*)(qL + 8388608);
    // conv3 overlay
    unsigned short* xpH = (unsigned short*)regA;      // 8,921,088 shorts
    unsigned short* xpL = xpH + 8921088;
    unsigned short* wtH = xpL + 8921088;              // 589,824 shorts
    unsigned short* wtL = wtH + 589824;
    // pipeline overlay
    float* kf = (float*)regA;                         // 2,097,152 floats
    float* vf = kf + 2097152;
    unsigned short* kTh = (unsigned short*)(vf + 2097152);
    unsigned short* kTl = kTh + 2097152;
    unsigned short* vH  = kTl + 2097152;
    unsigned short* vL  = vH + 2097152;
    float* stq = (float*)(vL + 2097152);
    float* stk = stq + 512;
    float* stv = stk + 512;
    // conv2 overlay (after kf,vf; dead once conv2x2_mfma finishes)
    unsigned short* yTh  = (unsigned short*)(vf + 2097152);   // 4,194,304 shorts (4 bat)
    unsigned short* yTl  = yTh + 4194304;
    unsigned short* w2kH = yTl + 4194304;                     // 262,144 shorts each
    unsigned short* w2kL = w2kH + 262144;
    unsigned short* w2vH = w2kL + 262144;
    unsigned short* w2vL = w2vH + 262144;

    // conv3x3 (q path) via MFMA
    hipMemsetAsync(xpH, 0, (size_t)2 * 8921088 * sizeof(unsigned short), stream);
    split_w_tap<<<256, 256, 0, stream>>>(Wq, wtH, wtL);
    split_x_pad<<<512, 256, 0, stream>>>(x, xpH, xpL);
    conv3x3_mfma<<<512, 256, 0, stream>>>(xpH, xpL, wtH, wtL, bq, qH, qL);

    // conv2x2 (k,v) via MFMA, two 4-batch halves (fits 71.6 MB workspace).
    split_w2<<<256, 256, 0, stream>>>(Wk, w2kH, w2kL);
    split_w2<<<256, 256, 0, stream>>>(Wv, w2vH, w2vL);
    split_y_t<<<256, 256, 0, stream>>>(y, yTh, yTl, 0);
    conv2x2_mfma<<<128, 256, 0, stream>>>(yTh, yTl, w2kH, w2kL, w2vH, w2vL,
                                          bk, bv, kf, vf, 0);
    split_y_t<<<256, 256, 0, stream>>>(y, yTh, yTl, 4);
    conv2x2_mfma<<<128, 256, 0, stream>>>(yTh, yTl, w2kH, w2kL, w2vH, w2vL,
                                          bk, bv, kf, vf, 4);

    gn_stats_pair<<<256, 256, 0, stream>>>(qH, qL, stq, 4096);
    gn_stats_kernel<<<256, 256, 0, stream>>>(kf, stk, 1024);
    gn_stats_kernel<<<256, 256, 0, stream>>>(vf, stv, 1024);
    gn_silu_pair<<<4096, 256, 0, stream>>>(qH, qL, stq, gqs, gqb, 0.0625f, 1048576);
    gn_silu_split_v<<<1024, 256, 0, stream>>>(vf, vH, vL, stv, gvs, gvb, 262144);
    gn_silu_split_kT<<<1024, 256, 0, stream>>>(kf, kTh, kTl, stk, gks, gkb);
    attn_mfma<<<1024, 256, 0, stream>>>(qH, qL, kTh, kTl, vH, vL, gamma, out);
}

// Round 6
// 712.346 us; speedup vs baseline: 1.7094x; 1.4832x over previous
//
#include <hip/hip_runtime.h>
#include <hip/hip_bf16.h>
#include <math.h>

#define B_ 8
#define C_ 256
#define H_ 64
#define W_ 64
#define N_ 4096
#define M_ 1024
#define HW_ 4096

typedef __attribute__((ext_vector_type(8))) short short8;
typedef __attribute__((ext_vector_type(4))) float f32x4;

__device__ __forceinline__ unsigned short f2bf(float x) {
    unsigned u = __float_as_uint(x);
    u += 0x7fffu + ((u >> 16) & 1u);          // round-to-nearest-even
    return (unsigned short)(u >> 16);
}
__device__ __forceinline__ float bf2f(unsigned short h) {
    return __uint_as_float(((unsigned)h) << 16);
}

// 16B async global->LDS (no VGPR round-trip). lds base wave-uniform; dest = base + lane*16.
__device__ __forceinline__ void gl_lds16(const unsigned short* g, unsigned short* l) {
    __builtin_amdgcn_global_load_lds(
        (const __attribute__((address_space(1))) unsigned int*)g,
        (__attribute__((address_space(3))) unsigned int*)l, 16, 0, 0);
}

// ---------------------------------------------------------------------------
// Split Wq [256co][256ci][3][3] fp32 -> per-tap bf16 hi/lo [9][256co][256ci].
__global__ __launch_bounds__(256) void split_w_tap(
    const float* __restrict__ Wq, unsigned short* __restrict__ wtH,
    unsigned short* __restrict__ wtL)
{
    int co = blockIdx.x, ci = threadIdx.x;
    const float* wp = Wq + ((size_t)co * 256 + ci) * 9;
    #pragma unroll
    for (int tap = 0; tap < 9; ++tap) {
        float v = wp[tap];
        unsigned short h = f2bf(v), l = f2bf(v - bf2f(h));
        size_t o = ((size_t)tap << 16) + ((size_t)co << 8) + ci;
        wtH[o] = h; wtL[o] = l;
    }
}

// Split W [256co][256ci][2][2] fp32 -> per-tap bf16 hi/lo [4][256co][256ci].
__global__ __launch_bounds__(256) void split_w2(
    const float* __restrict__ Wsrc, unsigned short* __restrict__ wH,
    unsigned short* __restrict__ wL)
{
    int co = blockIdx.x, ci = threadIdx.x;
    const float* wp = Wsrc + ((size_t)co * 256 + ci) * 4;
    #pragma unroll
    for (int tap = 0; tap < 4; ++tap) {
        float v = wp[tap];
        unsigned short h = f2bf(v), l = f2bf(v - bf2f(h));
        size_t o = ((size_t)tap << 16) + ((size_t)co << 8) + ci;
        wH[o] = h; wL[o] = l;
    }
}

// ---------------------------------------------------------------------------
// Transpose+split x [8][256][64][64] fp32 -> padded NHWC bf16 hi/lo
// [8][66][66][256] (halo pre-zeroed by memset). LDS-tiled transpose.
__global__ __launch_bounds__(256) void split_x_pad(
    const float* __restrict__ x, unsigned short* __restrict__ xpH,
    unsigned short* __restrict__ xpL)
{
    __shared__ float tile[64][65];
    int blk = blockIdx.x;            // b*64 + h
    int b = blk >> 6, h = blk & 63;
    int t = threadIdx.x;
    const float* xb = x + ((size_t)b << 20) + (size_t)h * 64;
    size_t obase = (((size_t)b * 4356) + (size_t)(h + 1) * 66 + 1) * 256;
    unsigned short* oH = xpH + obase;
    unsigned short* oL = xpL + obase;
    for (int cc = 0; cc < 256; cc += 64) {
        int wi = t & 63, cq = t >> 6;
        #pragma unroll
        for (int r = 0; r < 16; ++r) {
            int cl = cq * 16 + r;
            tile[cl][wi] = xb[((size_t)(cc + cl)) * 4096 + wi];
        }
        __syncthreads();
        int cl = t & 63, wq = t >> 6;
        #pragma unroll
        for (int r = 0; r < 16; ++r) {
            int wwi = wq * 16 + r;
            float v = tile[cl][wwi];
            unsigned short hh = f2bf(v), lo = f2bf(v - bf2f(hh));
            size_t o = (size_t)wwi * 256 + cc + cl;
            oH[o] = hh; oL[o] = lo;
        }
        __syncthreads();
    }
}

// Transpose+split y (4-batch half) fp32 -> NHWC bf16 hi/lo [4][64][64][256].
__global__ __launch_bounds__(256) void split_y_t(
    const float* __restrict__ y, unsigned short* __restrict__ yTh,
    unsigned short* __restrict__ yTl, int b0)
{
    __shared__ float tile[64][65];
    int blk = blockIdx.x;            // bl*64 + h, bl in [0,4)
    int bl = blk >> 6, h = blk & 63;
    int t = threadIdx.x;
    const float* yb = y + ((size_t)(b0 + bl) << 20) + (size_t)h * 64;
    size_t obase = (((size_t)bl << 12) + (size_t)h * 64) * 256;
    unsigned short* oH = yTh + obase;
    unsigned short* oL = yTl + obase;
    for (int cc = 0; cc < 256; cc += 64) {
        int wi = t & 63, cq = t >> 6;
        #pragma unroll
        for (int r = 0; r < 16; ++r) {
            int cl = cq * 16 + r;
            tile[cl][wi] = yb[((size_t)(cc + cl)) * 4096 + wi];
        }
        __syncthreads();
        int cl = t & 63, wq = t >> 6;
        #pragma unroll
        for (int r = 0; r < 16; ++r) {
            int wwi = wq * 16 + r;
            float v = tile[cl][wwi];
            unsigned short hh = f2bf(v), lo = f2bf(v - bf2f(hh));
            size_t o = (size_t)wwi * 256 + cc + cl;
            oH[o] = hh; oL[o] = lo;
        }
        __syncthreads();
    }
}

// ---------------------------------------------------------------------------
// conv 3x3 s1 p1 via MFMA: per-tap GEMM sum, split-bf16 3-term fp32 emulation.
__global__ __launch_bounds__(256, 2) void conv3x3_mfma(
    const unsigned short* __restrict__ xpH, const unsigned short* __restrict__ xpL,
    const unsigned short* __restrict__ wtH, const unsigned short* __restrict__ wtL,
    const float* __restrict__ bq,
    unsigned short* __restrict__ qH, unsigned short* __restrict__ qL)
{
    int blk = blockIdx.x;
    int bat = blk & 7;
    int rest = blk >> 3;
    int cot = rest & 1;
    int pxt = rest >> 1;                  // 32 tiles of 128 px (2 rows of 64)
    int t = threadIdx.x;
    int wv = t >> 6;
    int wco = wv >> 1, wpx = wv & 1;
    int lane = t & 63;
    int ll = lane & 15, qd = lane >> 4;

    const int co0 = cot * 128 + wco * 64;
    const unsigned short* aHp[4]; const unsigned short* aLp[4];
    #pragma unroll
    for (int ib = 0; ib < 4; ++ib) {
        size_t o = ((size_t)(co0 + ib * 16 + ll)) * 256 + qd * 8;
        aHp[ib] = wtH + o; aLp[ib] = wtL + o;
    }
    const unsigned short* bHp[4]; const unsigned short* bLp[4];
    const int h0 = pxt * 2;
    #pragma unroll
    for (int jb = 0; jb < 4; ++jb) {
        int pxl = wpx * 64 + jb * 16 + ll;
        int hh = h0 + (pxl >> 6);
        int ww = pxl & 63;
        size_t o = ((size_t)bat * 4356 + (size_t)hh * 66 + ww) * 256 + qd * 8;
        bHp[jb] = xpH + o; bLp[jb] = xpL + o;
    }

    f32x4 acc[4][4];
    #pragma unroll
    for (int i = 0; i < 4; ++i)
        #pragma unroll
        for (int j = 0; j < 4; ++j) acc[i][j] = (f32x4){0.f, 0.f, 0.f, 0.f};

    int boff = 0;   // (kh*66+kw)*256 shorts
    int kw = 0;
    for (int tap = 0; tap < 9; ++tap) {
        const int aoff = tap << 16;
        #pragma unroll 2
        for (int ci0 = 0; ci0 < 256; ci0 += 32) {
            short8 avh[4], avl[4], bvh[4], bvl[4];
            #pragma unroll
            for (int ib = 0; ib < 4; ++ib) {
                avh[ib] = *(const short8*)(aHp[ib] + aoff + ci0);
                avl[ib] = *(const short8*)(aLp[ib] + aoff + ci0);
            }
            #pragma unroll
            for (int jb = 0; jb < 4; ++jb) {
                bvh[jb] = *(const short8*)(bHp[jb] + boff + ci0);
                bvl[jb] = *(const short8*)(bLp[jb] + boff + ci0);
            }
            #pragma unroll
            for (int ib = 0; ib < 4; ++ib)
                #pragma unroll
                for (int jb = 0; jb < 4; ++jb) {
                    f32x4 o = acc[ib][jb];
                    o = __builtin_amdgcn_mfma_f32_16x16x32_bf16(avh[ib], bvh[jb], o, 0, 0, 0);
                    o = __builtin_amdgcn_mfma_f32_16x16x32_bf16(avl[ib], bvh[jb], o, 0, 0, 0);
                    o = __builtin_amdgcn_mfma_f32_16x16x32_bf16(avh[ib], bvl[jb], o, 0, 0, 0);
                    acc[ib][jb] = o;
                }
        }
        kw++;
        boff += 256;
        if (kw == 3) { kw = 0; boff += 63 * 256; }
    }

    const int pxbase = pxt * 128 + wpx * 64;
    #pragma unroll
    for (int ib = 0; ib < 4; ++ib) {
        #pragma unroll
        for (int r = 0; r < 4; ++r) {
            int co = co0 + ib * 16 + qd * 4 + r;
            float bvv = bq[co];
            size_t rowo = ((size_t)(bat * 256 + co)) << 12;
            #pragma unroll
            for (int jb = 0; jb < 4; ++jb) {
                float v = acc[ib][jb][r] + bvv;
                unsigned short h = f2bf(v), l = f2bf(v - bf2f(h));
                size_t o = rowo + pxbase + jb * 16 + ll;
                qH[o] = h; qL[o] = l;
            }
        }
    }
}

// ---------------------------------------------------------------------------
// conv 2x2 s2 p0 via MFMA (k and v), 4-batch half. Grid 128 = 4 bat x 4 sel
// x 8 m-tiles. Block 256 = 4 waves (2co x 2m). fp32 out (pre-GN).
__global__ __launch_bounds__(256, 2) void conv2x2_mfma(
    const unsigned short* __restrict__ yTh, const unsigned short* __restrict__ yTl,
    const unsigned short* __restrict__ wkH, const unsigned short* __restrict__ wkL,
    const unsigned short* __restrict__ wvH, const unsigned short* __restrict__ wvL,
    const float* __restrict__ bk, const float* __restrict__ bv,
    float* __restrict__ kf, float* __restrict__ vf, int b0)
{
    int blk = blockIdx.x;
    int batl = blk & 3;
    int sel = (blk >> 2) & 3;
    int mt  = blk >> 4;                   // 0..7, 128 m each
    int t = threadIdx.x;
    int wv_ = t >> 6;
    int wco = wv_ >> 1, wpx = wv_ & 1;
    int lane = t & 63;
    int ll = lane & 15, qd = lane >> 4;

    const unsigned short* wtH_; const unsigned short* wtL_;
    const float* bias; float* dst; int co0;
    if (sel < 2) { wtH_ = wkH; wtL_ = wkL; bias = bk; dst = kf; co0 = sel * 128 + wco * 64; }
    else         { wtH_ = wvH; wtL_ = wvL; bias = bv; dst = vf; co0 = (sel - 2) * 128 + wco * 64; }

    const unsigned short* aHp[4]; const unsigned short* aLp[4];
    #pragma unroll
    for (int ib = 0; ib < 4; ++ib) {
        size_t o = ((size_t)(co0 + ib * 16 + ll)) * 256 + qd * 8;
        aHp[ib] = wtH_ + o; aLp[ib] = wtL_ + o;
    }
    const unsigned short* bHp[4]; const unsigned short* bLp[4];
    #pragma unroll
    for (int jb = 0; jb < 4; ++jb) {
        int m = mt * 128 + wpx * 64 + jb * 16 + ll;
        int mh = m >> 5, mw = m & 31;
        size_t o = (((size_t)batl << 12) + (size_t)(2 * mh) * 64 + 2 * mw) * 256 + qd * 8;
        bHp[jb] = yTh + o; bLp[jb] = yTl + o;
    }

    f32x4 acc[4][4];
    #pragma unroll
    for (int i = 0; i < 4; ++i)
        #pragma unroll
        for (int j = 0; j < 4; ++j) acc[i][j] = (f32x4){0.f, 0.f, 0.f, 0.f};

    #pragma unroll
    for (int tap = 0; tap < 4; ++tap) {
        const int aoff = tap << 16;
        const int boff = (((tap >> 1) * 64) + (tap & 1)) * 256;
        #pragma unroll 2
        for (int ci0 = 0; ci0 < 256; ci0 += 32) {
            short8 avh[4], avl[4], bvh[4], bvl[4];
            #pragma unroll
            for (int ib = 0; ib < 4; ++ib) {
                avh[ib] = *(const short8*)(aHp[ib] + aoff + ci0);
                avl[ib] = *(const short8*)(aLp[ib] + aoff + ci0);
            }
            #pragma unroll
            for (int jb = 0; jb < 4; ++jb) {
                bvh[jb] = *(const short8*)(bHp[jb] + boff + ci0);
                bvl[jb] = *(const short8*)(bLp[jb] + boff + ci0);
            }
            #pragma unroll
            for (int ib = 0; ib < 4; ++ib)
                #pragma unroll
                for (int jb = 0; jb < 4; ++jb) {
                    f32x4 o = acc[ib][jb];
                    o = __builtin_amdgcn_mfma_f32_16x16x32_bf16(avh[ib], bvh[jb], o, 0, 0, 0);
                    o = __builtin_amdgcn_mfma_f32_16x16x32_bf16(avl[ib], bvh[jb], o, 0, 0, 0);
                    o = __builtin_amdgcn_mfma_f32_16x16x32_bf16(avh[ib], bvl[jb], o, 0, 0, 0);
                    acc[ib][jb] = o;
                }
        }
    }

    const int mbase = mt * 128 + wpx * 64;
    #pragma unroll
    for (int ib = 0; ib < 4; ++ib) {
        #pragma unroll
        for (int r = 0; r < 4; ++r) {
            int co = co0 + ib * 16 + qd * 4 + r;
            float bvv = bias[co];
            float* op = dst + (((size_t)((b0 + batl) * 256 + co)) << 10) + mbase + ll;
            #pragma unroll
            for (int jb = 0; jb < 4; ++jb)
                op[jb * 16] = acc[ib][jb][r] + bvv;
        }
    }
}

// ---------------------------------------------------------------------------
// GroupNorm stats (fp32 input): one block per (batch, group).
__global__ __launch_bounds__(256) void gn_stats_kernel(
    const float* __restrict__ buf, float* __restrict__ stats, int S)
{
    int bg = blockIdx.x;
    const float4* p = (const float4*)(buf + (size_t)bg * 8 * S);
    int n4 = 2 * S;
    float s = 0.f, s2 = 0.f;
    for (int i = threadIdx.x; i < n4; i += 256) {
        float4 vv = p[i];
        s  += vv.x + vv.y + vv.z + vv.w;
        s2 += vv.x * vv.x + vv.y * vv.y + vv.z * vv.z + vv.w * vv.w;
    }
    for (int d = 1; d < 64; d <<= 1) { s += __shfl_xor(s, d); s2 += __shfl_xor(s2, d); }
    __shared__ float red[8];
    int w = threadIdx.x >> 6;
    if ((threadIdx.x & 63) == 0) { red[w] = s; red[w + 4] = s2; }
    __syncthreads();
    if (threadIdx.x == 0) {
        s  = red[0] + red[1] + red[2] + red[3];
        s2 = red[4] + red[5] + red[6] + red[7];
        float invn = 1.f / (float)(8 * S);
        float mean = s * invn;
        float var = s2 * invn - mean * mean;
        if (var < 0.f) var = 0.f;
        stats[bg * 2]     = mean;
        stats[bg * 2 + 1] = 1.f / sqrtf(var + 1e-5f);
    }
}

// GroupNorm stats from bf16 hi/lo pair (q path).
__global__ __launch_bounds__(256) void gn_stats_pair(
    const unsigned short* __restrict__ hi, const unsigned short* __restrict__ lo,
    float* __restrict__ stats, int S)
{
    int bg = blockIdx.x;
    const uint4* ph = (const uint4*)(hi + (size_t)bg * 8 * S);
    const uint4* pl = (const uint4*)(lo + (size_t)bg * 8 * S);
    int n8 = S;
    float s = 0.f, s2 = 0.f;
    for (int i = threadIdx.x; i < n8; i += 256) {
        uint4 a = ph[i], b2 = pl[i];
        unsigned ua[4] = {a.x, a.y, a.z, a.w}, ub[4] = {b2.x, b2.y, b2.z, b2.w};
        #pragma unroll
        for (int j = 0; j < 4; ++j) {
            float x0 = __uint_as_float(ua[j] << 16) + __uint_as_float(ub[j] << 16);
            float x1 = __uint_as_float(ua[j] & 0xffff0000u) + __uint_as_float(ub[j] & 0xffff0000u);
            s += x0 + x1;
            s2 += x0 * x0 + x1 * x1;
        }
    }
    for (int d = 1; d < 64; d <<= 1) { s += __shfl_xor(s, d); s2 += __shfl_xor(s2, d); }
    __shared__ float red[8];
    int w = threadIdx.x >> 6;
    if ((threadIdx.x & 63) == 0) { red[w] = s; red[w + 4] = s2; }
    __syncthreads();
    if (threadIdx.x == 0) {
        s  = red[0] + red[1] + red[2] + red[3];
        s2 = red[4] + red[5] + red[6] + red[7];
        float invn = 1.f / (float)(8 * S);
        float mean = s * invn;
        float var = s2 * invn - mean * mean;
        if (var < 0.f) var = 0.f;
        stats[bg * 2]     = mean;
        stats[bg * 2 + 1] = 1.f / sqrtf(var + 1e-5f);
    }
}

// GN + affine + SiLU (+extra scale) on bf16 pair, in place (q path, N=4096).
__global__ __launch_bounds__(256) void gn_silu_pair(
    unsigned short* __restrict__ hi, unsigned short* __restrict__ lo,
    const float* __restrict__ stats, const float* __restrict__ scale,
    const float* __restrict__ bias, float extra, int total8)
{
    int idx = blockIdx.x * 256 + threadIdx.x;
    if (idx >= total8) return;
    size_t e = (size_t)idx * 8;
    int c  = (int)((e >> 12) & 255);
    int gg = (int)(e >> 15);
    float mean = stats[gg * 2], rstd = stats[gg * 2 + 1];
    float a  = scale[c] * rstd;
    float bb = bias[c] - mean * a;
    uint4 uh = ((uint4*)hi)[idx], ul = ((uint4*)lo)[idx];
    unsigned ha[4] = {uh.x, uh.y, uh.z, uh.w}, la[4] = {ul.x, ul.y, ul.z, ul.w};
    unsigned oh[4], ol[4];
    #pragma unroll
    for (int j = 0; j < 4; ++j) {
        float x0 = __uint_as_float(ha[j] << 16) + __uint_as_float(la[j] << 16);
        float x1 = __uint_as_float(ha[j] & 0xffff0000u) + __uint_as_float(la[j] & 0xffff0000u);
        float y0 = x0 * a + bb, y1 = x1 * a + bb;
        float s0 = extra * y0 / (1.f + __expf(-y0));
        float s1 = extra * y1 / (1.f + __expf(-y1));
        unsigned short h0 = f2bf(s0), l0 = f2bf(s0 - bf2f(h0));
        unsigned short h1 = f2bf(s1), l1 = f2bf(s1 - bf2f(h1));
        oh[j] = h0 | ((unsigned)h1 << 16);
        ol[j] = l0 | ((unsigned)l1 << 16);
    }
    ((uint4*)hi)[idx] = make_uint4(oh[0], oh[1], oh[2], oh[3]);
    ((uint4*)lo)[idx] = make_uint4(ol[0], ol[1], ol[2], ol[3]);
}

// GN + affine + SiLU on fp32 v -> bf16 hi/lo pair, natural [C][M] layout.
__global__ __launch_bounds__(256) void gn_silu_split_v(
    const float* __restrict__ vf, unsigned short* __restrict__ hi,
    unsigned short* __restrict__ lo, const float* __restrict__ stats,
    const float* __restrict__ scale, const float* __restrict__ bias, int total8)
{
    int idx = blockIdx.x * 256 + threadIdx.x;
    if (idx >= total8) return;
    size_t e = (size_t)idx * 8;
    int c  = (int)((e >> 10) & 255);
    int gg = (int)(e >> 13);
    float mean = stats[gg * 2], rstd = stats[gg * 2 + 1];
    float a  = scale[c] * rstd;
    float bb = bias[c] - mean * a;
    float4 f0 = ((const float4*)vf)[idx * 2];
    float4 f1 = ((const float4*)vf)[idx * 2 + 1];
    float xs[8] = {f0.x, f0.y, f0.z, f0.w, f1.x, f1.y, f1.z, f1.w};
    unsigned oh[4], ol[4];
    #pragma unroll
    for (int j = 0; j < 4; ++j) {
        float y0 = xs[2 * j] * a + bb, y1 = xs[2 * j + 1] * a + bb;
        float s0 = y0 / (1.f + __expf(-y0));
        float s1 = y1 / (1.f + __expf(-y1));
        unsigned short h0 = f2bf(s0), l0 = f2bf(s0 - bf2f(h0));
        unsigned short h1 = f2bf(s1), l1 = f2bf(s1 - bf2f(h1));
        oh[j] = h0 | ((unsigned)h1 << 16);
        ol[j] = l0 | ((unsigned)l1 << 16);
    }
    ((uint4*)hi)[idx] = make_uint4(oh[0], oh[1], oh[2], oh[3]);
    ((uint4*)lo)[idx] = make_uint4(ol[0], ol[1], ol[2], ol[3]);
}

// GN + affine + SiLU on fp32 k -> TRANSPOSED bf16 hi/lo [B][M][C] (B-frag layout).
__global__ __launch_bounds__(256) void gn_silu_split_kT(
    const float* __restrict__ kf, unsigned short* __restrict__ th,
    unsigned short* __restrict__ tl, const float* __restrict__ stats,
    const float* __restrict__ scale, const float* __restrict__ bias)
{
    int bm = blockIdx.x;              // 8 batches * 128 m8-groups
    int b = bm >> 7, m8 = (bm & 127) * 8;
    int c = threadIdx.x;
    int gg = b * 32 + (c >> 3);
    float mean = stats[gg * 2], rstd = stats[gg * 2 + 1];
    float a  = scale[c] * rstd;
    float bb = bias[c] - mean * a;
    const float* src = kf + (((size_t)(b * 256 + c)) << 10) + m8;
    float4 f0 = *(const float4*)src;
    float4 f1 = *(const float4*)(src + 4);
    float xs[8] = {f0.x, f0.y, f0.z, f0.w, f1.x, f1.y, f1.z, f1.w};
    #pragma unroll
    for (int j = 0; j < 8; ++j) {
        float y = xs[j] * a + bb;
        float s = y / (1.f + __expf(-y));
        unsigned short h = f2bf(s), l = f2bf(s - bf2f(h));
        size_t o = ((size_t)b * M_ + m8 + j) * C_ + c;
        th[o] = h;
        tl[o] = l;
    }
}

// ---------------------------------------------------------------------------
// Fused flash attention, split-bf16 MFMA, LDS-STAGED K/V pipeline.
// Grid 512 = 8 bat x 64 nt (64 q-rows). Block 256 = 4 q-waves (16 rows each),
// all sharing the same m-tile stream (32 m per tile, 32 tiles).
// Per tile: cooperative global_load_lds staging of K(hi,lo)+V(hi,lo) (64KB,
// swizzled: K colg^=row&7, V granule^=c&3 -> conflict-free ds_read_b128),
// barrier, then QK/softmax/PV entirely from LDS. No VGPRs burned on operand
// loads -> load latency decoupled from the 2-wave/SIMD register regime.
__global__ __launch_bounds__(256, 2) void attn_mfma(
    const unsigned short* __restrict__ qh, const unsigned short* __restrict__ qlo,
    const unsigned short* __restrict__ kth, const unsigned short* __restrict__ ktl,
    const unsigned short* __restrict__ vh, const unsigned short* __restrict__ vlo,
    const float* __restrict__ gamma, float* __restrict__ out)
{
    __shared__ __align__(16) unsigned short kldsH[32 * 256];   // 16KB [m][Cg^ (m&7)]
    __shared__ __align__(16) unsigned short kldsL[32 * 256];
    __shared__ __align__(16) unsigned short vldsH[256 * 32];   // 16KB [c][g ^ (c&3)]
    __shared__ __align__(16) unsigned short vldsL[256 * 32];
    __shared__ __align__(16) unsigned short pH[4][16][40];
    __shared__ __align__(16) unsigned short pL[4][16][40];
    __shared__ float alphaS[4][16];

    int blk = blockIdx.x;
    int bat = blk & 7;
    int nt  = blk >> 3;           // 0..63
    int t = threadIdx.x;
    int w = t >> 6;               // q-wave 0..3
    int lane = t & 63;
    int ll = lane & 15;
    int qd = lane >> 4;
    int n0 = nt * 64 + w * 16;

    // Q A-frags held in registers (one-time load)
    short8 aqh[8], aql[8];
    {
        const unsigned short* qb1 = qh  + (size_t)bat * C_ * N_ + n0 + ll;
        const unsigned short* qb2 = qlo + (size_t)bat * C_ * N_ + n0 + ll;
        #pragma unroll
        for (int ks = 0; ks < 8; ++ks) {
            #pragma unroll
            for (int j = 0; j < 8; ++j) {
                size_t off = (size_t)(ks * 32 + qd * 8 + j) * N_;
                aqh[ks][j] = (short)qb1[off];
                aql[ks][j] = (short)qb2[off];
            }
        }
    }

    f32x4 oacc[16];
    #pragma unroll
    for (int i = 0; i < 16; ++i) oacc[i] = (f32x4){0.f, 0.f, 0.f, 0.f};
    f32x4 lacc = (f32x4){0.f, 0.f, 0.f, 0.f};
    float mrun[4] = {-3e38f, -3e38f, -3e38f, -3e38f};
    const short8 ones = (short8){16256, 16256, 16256, 16256, 16256, 16256, 16256, 16256};

    // staging role per wave: 0=K.hi 1=K.lo 2=V.hi 3=V.lo
    const unsigned short* kg = ((w & 1) == 0 ? kth : ktl) + (size_t)bat * M_ * C_;
    const unsigned short* vg = ((w & 1) == 0 ? vh  : vlo) + (size_t)bat * C_ * M_;
    unsigned short* kdst = (w & 1) ? kldsL : kldsH;
    unsigned short* vdst = (w & 1) ? vldsL : vldsH;
    const int krow  = lane >> 5;          // 0/1
    const int kcolg = lane & 31;          // 16B granule within 512B row
    const int vc_l  = lane >> 2;          // 0..15 c-row within 16
    const int vg_g  = lane & 3;           // 16B granule within 64B row

    for (int mt = 0; mt < 32; ++mt) {
        const int m0 = mt * 32;
        // ---- stage K/V tile into LDS (wave-specialized, pre-swizzled source)
        if (w < 2) {
            #pragma unroll
            for (int i = 0; i < 16; ++i) {
                int row = 2 * i + krow;
                const unsigned short* src = kg + (size_t)(m0 + row) * 256
                                            + ((kcolg ^ (row & 7)) << 3);
                gl_lds16(src, kdst + i * 512);
            }
        } else {
            #pragma unroll
            for (int i = 0; i < 16; ++i) {
                int c = i * 16 + vc_l;
                const unsigned short* src = vg + (size_t)c * M_ + m0
                                            + ((vg_g ^ (c & 3)) << 3);
                gl_lds16(src, vdst + i * 512);
            }
        }
        __syncthreads();   // drains vmcnt (global_load_lds) + lgkmcnt

        // ---- QK^T from LDS (B-frags: lane ll = m-col, qd*8+ks*32 = C-chunk)
        f32x4 s0 = {0.f, 0.f, 0.f, 0.f}, s1 = {0.f, 0.f, 0.f, 0.f};
        __builtin_amdgcn_s_setprio(1);
        #pragma unroll
        for (int ks = 0; ks < 8; ++ks) {
            int cg = ks * 4 + qd;
            int a0 = ll * 256 + ((cg ^ (ll & 7)) << 3);
            int a1 = (ll + 16) * 256 + ((cg ^ (ll & 7)) << 3);
            short8 b0h = *(const short8*)&kldsH[a0];
            short8 b1h = *(const short8*)&kldsH[a1];
            short8 b0l = *(const short8*)&kldsL[a0];
            short8 b1l = *(const short8*)&kldsL[a1];
            s0 = __builtin_amdgcn_mfma_f32_16x16x32_bf16(aqh[ks], b0h, s0, 0, 0, 0);
            s1 = __builtin_amdgcn_mfma_f32_16x16x32_bf16(aqh[ks], b1h, s1, 0, 0, 0);
            s0 = __builtin_amdgcn_mfma_f32_16x16x32_bf16(aql[ks], b0h, s0, 0, 0, 0);
            s1 = __builtin_amdgcn_mfma_f32_16x16x32_bf16(aql[ks], b1h, s1, 0, 0, 0);
            s0 = __builtin_amdgcn_mfma_f32_16x16x32_bf16(aqh[ks], b0l, s0, 0, 0, 0);
            s1 = __builtin_amdgcn_mfma_f32_16x16x32_bf16(aqh[ks], b1l, s1, 0, 0, 0);
        }
        __builtin_amdgcn_s_setprio(0);

        // ---- online softmax (max only; row-sum via ones-MFMA below)
        float alpha4[4];
        #pragma unroll
        for (int r = 0; r < 4; ++r) {
            float mx = fmaxf(s0[r], s1[r]);
            mx = fmaxf(mx, __shfl_xor(mx, 1));
            mx = fmaxf(mx, __shfl_xor(mx, 2));
            mx = fmaxf(mx, __shfl_xor(mx, 4));
            mx = fmaxf(mx, __shfl_xor(mx, 8));
            float mn = fmaxf(mrun[r], mx);
            float al = __expf(mrun[r] - mn);
            mrun[r] = mn;
            float p0 = __expf(s0[r] - mn);
            float p1 = __expf(s1[r] - mn);
            alpha4[r] = al;
            unsigned short h0 = f2bf(p0), l0 = f2bf(p0 - bf2f(h0));
            unsigned short h1 = f2bf(p1), l1 = f2bf(p1 - bf2f(h1));
            int rn = qd * 4 + r;
            pH[w][rn][ll] = h0;  pH[w][rn][16 + ll] = h1;
            pL[w][rn][ll] = l0;  pL[w][rn][16 + ll] = l1;
        }
        if (ll == 0) {
            #pragma unroll
            for (int r = 0; r < 4; ++r) alphaS[w][qd * 4 + r] = alpha4[r];
        }
        __builtin_amdgcn_wave_barrier();   // intra-wave LDS RAW (per-wave slab)
        short8 bph = *(const short8*)&pH[w][ll][qd * 8];
        short8 bpl = *(const short8*)&pL[w][ll][qd * 8];
        float an = alphaS[w][ll];
        // l accumulation via ones-MFMA (row-sum of P, lane-aligned by q-row)
        {
            f32x4 o = lacc;
            o[0] *= an; o[1] *= an; o[2] *= an; o[3] *= an;
            o = __builtin_amdgcn_mfma_f32_16x16x32_bf16(ones, bph, o, 0, 0, 0);
            o = __builtin_amdgcn_mfma_f32_16x16x32_bf16(ones, bpl, o, 0, 0, 0);
            lacc = o;
        }
        // ---- PV from LDS (A-frags: lane ll = c-row within ct, qd*8 = m-chunk)
        __builtin_amdgcn_s_setprio(1);
        #pragma unroll
        for (int ct = 0; ct < 16; ++ct) {
            int c = ct * 16 + ll;
            int av = c * 32 + ((qd ^ (c & 3)) << 3);
            short8 avh = *(const short8*)&vldsH[av];
            short8 avl = *(const short8*)&vldsL[av];
            f32x4 o = oacc[ct];
            o[0] *= an; o[1] *= an; o[2] *= an; o[3] *= an;
            o = __builtin_amdgcn_mfma_f32_16x16x32_bf16(avh, bph, o, 0, 0, 0);
            o = __builtin_amdgcn_mfma_f32_16x16x32_bf16(avl, bph, o, 0, 0, 0);
            o = __builtin_amdgcn_mfma_f32_16x16x32_bf16(avh, bpl, o, 0, 0, 0);
            oacc[ct] = o;
        }
        __builtin_amdgcn_s_setprio(0);
        __syncthreads();   // all waves done reading before next stage overwrites
    }

    // ---- epilogue: normalize by lacc (lane-aligned l), no cross-wave merge
    float linv = gamma[0] / lacc[0];
    float* ob = out + (size_t)bat * C_ * N_ + n0 + ll;
    #pragma unroll
    for (int ct = 0; ct < 16; ++ct) {
        #pragma unroll
        for (int r = 0; r < 4; ++r) {
            int c = ct * 16 + qd * 4 + r;
            ob[(size_t)c * N_] = oacc[ct][r] * linv;
        }
    }
}

// ---------------------------------------------------------------------------
extern "C" void kernel_launch(void* const* d_in, const int* in_sizes, int n_in,
                              void* d_out, int out_size, void* d_ws, size_t ws_size,
                              hipStream_t stream)
{
    const float* x   = (const float*)d_in[0];
    const float* y   = (const float*)d_in[1];
    const float* Wq  = (const float*)d_in[2];
    const float* bq  = (const float*)d_in[3];
    const float* gqs = (const float*)d_in[4];
    const float* gqb = (const float*)d_in[5];
    const float* Wk  = (const float*)d_in[6];
    const float* bk  = (const float*)d_in[7];
    const float* gks = (const float*)d_in[8];
    const float* gkb = (const float*)d_in[9];
    const float* Wv  = (const float*)d_in[10];
    const float* bv  = (const float*)d_in[11];
    const float* gvs = (const float*)d_in[12];
    const float* gvb = (const float*)d_in[13];
    const float* gamma = (const float*)d_in[14];
    float* out = (float*)d_out;

    // ws layout (71.6 MB total, all phases):
    //   qH, qL: 2 x 16.78 MB
    //   regA (phase-overlaid, 38.05 MB):
    //     conv3 phase:  xpH,xpL [8][66][66][256] bf16 + wtH,wtL       (38.05 MB)
    //     conv2 phase:  kf,vf fp32 (16.78) | yT half-batch (16.78) | w2 (2.10)
    //     gn/attn:      kf,vf | kTh,kTl,vH,vL | stats                 (33.57 MB)
    char* base = (char*)d_ws;
    unsigned short* qH = (unsigned short*)base;
    unsigned short* qL = qH + 8388608;
    char* regA = (char*)(qL + 8388608);
    // conv3 overlay
    unsigned short* xpH = (unsigned short*)regA;      // 8,921,088 shorts
    unsigned short* xpL = xpH + 8921088;
    unsigned short* wtH = xpL + 8921088;              // 589,824 shorts
    unsigned short* wtL = wtH + 589824;
    // pipeline overlay
    float* kf = (float*)regA;                         // 2,097,152 floats
    float* vf = kf + 2097152;
    unsigned short* kTh = (unsigned short*)(vf + 2097152);
    unsigned short* kTl = kTh + 2097152;
    unsigned short* vH  = kTl + 2097152;
    unsigned short* vL  = vH + 2097152;
    float* stq = (float*)(vL + 2097152);
    float* stk = stq + 512;
    float* stv = stk + 512;
    // conv2 overlay (after kf,vf; dead once conv2x2_mfma finishes)
    unsigned short* yTh  = (unsigned short*)(vf + 2097152);   // 4,194,304 shorts (4 bat)
    unsigned short* yTl  = yTh + 4194304;
    unsigned short* w2kH = yTl + 4194304;                     // 262,144 shorts each
    unsigned short* w2kL = w2kH + 262144;
    unsigned short* w2vH = w2kL + 262144;
    unsigned short* w2vL = w2vH + 262144;

    // conv3x3 (q path) via MFMA
    hipMemsetAsync(xpH, 0, (size_t)2 * 8921088 * sizeof(unsigned short), stream);
    split_w_tap<<<256, 256, 0, stream>>>(Wq, wtH, wtL);
    split_x_pad<<<512, 256, 0, stream>>>(x, xpH, xpL);
    conv3x3_mfma<<<512, 256, 0, stream>>>(xpH, xpL, wtH, wtL, bq, qH, qL);

    // conv2x2 (k,v) via MFMA, two 4-batch halves (fits 71.6 MB workspace).
    split_w2<<<256, 256, 0, stream>>>(Wk, w2kH, w2kL);
    split_w2<<<256, 256, 0, stream>>>(Wv, w2vH, w2vL);
    split_y_t<<<256, 256, 0, stream>>>(y, yTh, yTl, 0);
    conv2x2_mfma<<<128, 256, 0, stream>>>(yTh, yTl, w2kH, w2kL, w2vH, w2vL,
                                          bk, bv, kf, vf, 0);
    split_y_t<<<256, 256, 0, stream>>>(y, yTh, yTl, 4);
    conv2x2_mfma<<<128, 256, 0, stream>>>(yTh, yTl, w2kH, w2kL, w2vH, w2vL,
                                          bk, bv, kf, vf, 4);

    gn_stats_pair<<<256, 256, 0, stream>>>(qH, qL, stq, 4096);
    gn_stats_kernel<<<256, 256, 0, stream>>>(kf, stk, 1024);
    gn_stats_kernel<<<256, 256, 0, stream>>>(vf, stv, 1024);
    gn_silu_pair<<<4096, 256, 0, stream>>>(qH, qL, stq, gqs, gqb, 0.0625f, 1048576);
    gn_silu_split_v<<<1024, 256, 0, stream>>>(vf, vH, vL, stv, gvs, gvb, 262144);
    gn_silu_split_kT<<<1024, 256, 0, stream>>>(kf, kTh, kTl, stk, gks, gkb);
    attn_mfma<<<512, 256, 0, stream>>>(qH, qL, kTh, kTl, vH, vL, gamma, out);
}

// Round 7
// 559.467 us; speedup vs baseline: 2.1765x; 1.2733x over previous
//
#include <hip/hip_runtime.h>
#include <hip/hip_bf16.h>
#include <math.h>

#define B_ 8
#define C_ 256
#define H_ 64
#define W_ 64
#define N_ 4096
#define M_ 1024
#define HW_ 4096

typedef __attribute__((ext_vector_type(8))) short short8;
typedef __attribute__((ext_vector_type(4))) float f32x4;

__device__ __forceinline__ unsigned short f2bf(float x) {
    unsigned u = __float_as_uint(x);
    u += 0x7fffu + ((u >> 16) & 1u);          // round-to-nearest-even
    return (unsigned short)(u >> 16);
}
__device__ __forceinline__ float bf2f(unsigned short h) {
    return __uint_as_float(((unsigned)h) << 16);
}

// 16B async global->LDS (no VGPR round-trip). lds base wave-uniform; dest = base + lane*16.
__device__ __forceinline__ void gl_lds16(const unsigned short* g, unsigned short* l) {
    __builtin_amdgcn_global_load_lds(
        (const __attribute__((address_space(1))) unsigned int*)g,
        (__attribute__((address_space(3))) unsigned int*)l, 16, 0, 0);
}

// ---------------------------------------------------------------------------
// Split Wq [256co][256ci][3][3] fp32 -> per-tap bf16 hi/lo [9][256co][256ci].
__global__ __launch_bounds__(256) void split_w_tap(
    const float* __restrict__ Wq, unsigned short* __restrict__ wtH,
    unsigned short* __restrict__ wtL)
{
    int co = blockIdx.x, ci = threadIdx.x;
    const float* wp = Wq + ((size_t)co * 256 + ci) * 9;
    #pragma unroll
    for (int tap = 0; tap < 9; ++tap) {
        float v = wp[tap];
        unsigned short h = f2bf(v), l = f2bf(v - bf2f(h));
        size_t o = ((size_t)tap << 16) + ((size_t)co << 8) + ci;
        wtH[o] = h; wtL[o] = l;
    }
}

// Split W [256co][256ci][2][2] fp32 -> per-tap bf16 hi/lo [4][256co][256ci].
__global__ __launch_bounds__(256) void split_w2(
    const float* __restrict__ Wsrc, unsigned short* __restrict__ wH,
    unsigned short* __restrict__ wL)
{
    int co = blockIdx.x, ci = threadIdx.x;
    const float* wp = Wsrc + ((size_t)co * 256 + ci) * 4;
    #pragma unroll
    for (int tap = 0; tap < 4; ++tap) {
        float v = wp[tap];
        unsigned short h = f2bf(v), l = f2bf(v - bf2f(h));
        size_t o = ((size_t)tap << 16) + ((size_t)co << 8) + ci;
        wH[o] = h; wL[o] = l;
    }
}

// ---------------------------------------------------------------------------
// Transpose+split x [8][256][64][64] fp32 -> padded NHWC bf16 hi/lo
// [8][66][66][256] (halo pre-zeroed by memset). LDS-tiled transpose.
__global__ __launch_bounds__(256) void split_x_pad(
    const float* __restrict__ x, unsigned short* __restrict__ xpH,
    unsigned short* __restrict__ xpL)
{
    __shared__ float tile[64][65];
    int blk = blockIdx.x;            // b*64 + h
    int b = blk >> 6, h = blk & 63;
    int t = threadIdx.x;
    const float* xb = x + ((size_t)b << 20) + (size_t)h * 64;
    size_t obase = (((size_t)b * 4356) + (size_t)(h + 1) * 66 + 1) * 256;
    unsigned short* oH = xpH + obase;
    unsigned short* oL = xpL + obase;
    for (int cc = 0; cc < 256; cc += 64) {
        int wi = t & 63, cq = t >> 6;
        #pragma unroll
        for (int r = 0; r < 16; ++r) {
            int cl = cq * 16 + r;
            tile[cl][wi] = xb[((size_t)(cc + cl)) * 4096 + wi];
        }
        __syncthreads();
        int cl = t & 63, wq = t >> 6;
        #pragma unroll
        for (int r = 0; r < 16; ++r) {
            int wwi = wq * 16 + r;
            float v = tile[cl][wwi];
            unsigned short hh = f2bf(v), lo = f2bf(v - bf2f(hh));
            size_t o = (size_t)wwi * 256 + cc + cl;
            oH[o] = hh; oL[o] = lo;
        }
        __syncthreads();
    }
}

// Transpose+split y (4-batch half) fp32 -> NHWC bf16 hi/lo [4][64][64][256].
__global__ __launch_bounds__(256) void split_y_t(
    const float* __restrict__ y, unsigned short* __restrict__ yTh,
    unsigned short* __restrict__ yTl, int b0)
{
    __shared__ float tile[64][65];
    int blk = blockIdx.x;            // bl*64 + h, bl in [0,4)
    int bl = blk >> 6, h = blk & 63;
    int t = threadIdx.x;
    const float* yb = y + ((size_t)(b0 + bl) << 20) + (size_t)h * 64;
    size_t obase = (((size_t)bl << 12) + (size_t)h * 64) * 256;
    unsigned short* oH = yTh + obase;
    unsigned short* oL = yTl + obase;
    for (int cc = 0; cc < 256; cc += 64) {
        int wi = t & 63, cq = t >> 6;
        #pragma unroll
        for (int r = 0; r < 16; ++r) {
            int cl = cq * 16 + r;
            tile[cl][wi] = yb[((size_t)(cc + cl)) * 4096 + wi];
        }
        __syncthreads();
        int cl = t & 63, wq = t >> 6;
        #pragma unroll
        for (int r = 0; r < 16; ++r) {
            int wwi = wq * 16 + r;
            float v = tile[cl][wwi];
            unsigned short hh = f2bf(v), lo = f2bf(v - bf2f(hh));
            size_t o = (size_t)wwi * 256 + cc + cl;
            oH[o] = hh; oL[o] = lo;
        }
        __syncthreads();
    }
}

// ---------------------------------------------------------------------------
// conv 3x3 s1 p1 via MFMA, LDS-STAGED operands.
// Grid 512 = 8 bat x 2 cot x 32 pxt (128px = 2 rows of 64). Block 256 = 4
// waves (2co x 2px). ci-chunk OUTER (8), tap INNER (9): x-tile B [4][66][32]
// hi+lo staged once per chunk (reused by 9 taps); weight tile A [128][32]
// hi+lo double-buffered, next tap's stage issued before current tap's MFMAs.
// All staging via global_load_lds (fire-and-forget); frag reads ds_read_b128
// with granule swizzle g^=cell&3 (attn-V proven pattern).
__global__ __launch_bounds__(256, 2) void conv3x3_mfma(
    const unsigned short* __restrict__ xpH, const unsigned short* __restrict__ xpL,
    const unsigned short* __restrict__ wtH, const unsigned short* __restrict__ wtL,
    const float* __restrict__ bq,
    unsigned short* __restrict__ qH, unsigned short* __restrict__ qL)
{
    __shared__ __align__(16) unsigned short bldsH[272 * 32];   // 17.4KB x-tile hi
    __shared__ __align__(16) unsigned short bldsL[272 * 32];   // (264 cells + pad)
    __shared__ __align__(16) unsigned short aldsH[2][128 * 32]; // 8KB/buf weights hi
    __shared__ __align__(16) unsigned short aldsL[2][128 * 32];

    int blk = blockIdx.x;
    int bat = blk & 7;
    int rest = blk >> 3;
    int cot = rest & 1;
    int pxt = rest >> 1;                  // 32 tiles of 128 px (2 rows of 64)
    int t = threadIdx.x;
    int w = t >> 6;
    int wco = w >> 1, wpx = w & 1;
    int lane = t & 63;
    int ll = lane & 15, qd = lane >> 4;
    const int h0 = pxt * 2;               // padded-coords row base
    const int co0b = cot * 128;

    const unsigned short* xpHb = xpH + (size_t)bat * 4356 * 256;
    const unsigned short* xpLb = xpL + (size_t)bat * 4356 * 256;

    f32x4 acc[4][4];
    #pragma unroll
    for (int i = 0; i < 4; ++i)
        #pragma unroll
        for (int j = 0; j < 4; ++j) acc[i][j] = (f32x4){0.f, 0.f, 0.f, 0.f};

    int buf = 0;
    for (int chunk = 0; chunk < 8; ++chunk) {
        const int ci0 = chunk * 32;
        // ---- stage B x-tile: rows h0..h0+3, cols 0..65, 32 ci (hi+lo)
        for (int j = w; j < 34; j += 4) {
            int half = (j >= 17);
            int jj = half ? j - 17 : j;
            int gid = jj * 64 + lane;                 // 0..1087
            int cell = gid >> 2;
            int g = gid & 3;
            int cellc = cell < 264 ? cell : 263;      // clamp pad cells
            int dr = cellc / 66;
            int cc = cellc - dr * 66;
            const unsigned short* src = (half ? xpLb : xpHb)
                + (((size_t)(h0 + dr) * 66 + cc) << 8) + ci0
                + ((g ^ (cellc & 3)) << 3);
            unsigned short* dst = (half ? bldsL : bldsH) + jj * 512;
            gl_lds16(src, dst);
        }
        // ---- stage A weights, tap 0 -> buf
        for (int j = w; j < 16; j += 4) {
            int half = j >> 3;
            int jj = j & 7;
            int gid = jj * 64 + lane;                 // 0..511
            int co = gid >> 2;
            int g = gid & 3;
            const unsigned short* src = (half ? wtL : wtH)
                + (((size_t)(co0b + co)) << 8) + ci0 + ((g ^ (co & 3)) << 3);
            unsigned short* dst = (half ? aldsL[buf] : aldsH[buf]) + jj * 512;
            gl_lds16(src, dst);
        }
        __syncthreads();

        for (int tap = 0; tap < 9; ++tap) {
            // prefetch A for next tap into the other buffer (lands by barrier)
            if (tap < 8) {
                const int aoff = (tap + 1) << 16;
                for (int j = w; j < 16; j += 4) {
                    int half = j >> 3;
                    int jj = j & 7;
                    int gid = jj * 64 + lane;
                    int co = gid >> 2;
                    int g = gid & 3;
                    const unsigned short* src = (half ? wtL : wtH)
                        + aoff + (((size_t)(co0b + co)) << 8) + ci0
                        + ((g ^ (co & 3)) << 3);
                    unsigned short* dst = (half ? aldsL[buf ^ 1] : aldsH[buf ^ 1]) + jj * 512;
                    gl_lds16(src, dst);
                }
            }
            int kh = tap / 3, kw = tap - kh * 3;
            short8 avh[4], avl[4], bvh[4], bvl[4];
            #pragma unroll
            for (int ib = 0; ib < 4; ++ib) {
                int col = wco * 64 + ib * 16 + ll;
                int aa = col * 32 + ((qd ^ (col & 3)) << 3);
                avh[ib] = *(const short8*)&aldsH[buf][aa];
                avl[ib] = *(const short8*)&aldsL[buf][aa];
            }
            #pragma unroll
            for (int jb = 0; jb < 4; ++jb) {
                int cell = (wpx + kh) * 66 + jb * 16 + ll + kw;
                int ba = cell * 32 + ((qd ^ (cell & 3)) << 3);
                bvh[jb] = *(const short8*)&bldsH[ba];
                bvl[jb] = *(const short8*)&bldsL[ba];
            }
            __builtin_amdgcn_s_setprio(1);
            #pragma unroll
            for (int ib = 0; ib < 4; ++ib)
                #pragma unroll
                for (int jb = 0; jb < 4; ++jb) {
                    f32x4 o = acc[ib][jb];
                    o = __builtin_amdgcn_mfma_f32_16x16x32_bf16(avh[ib], bvh[jb], o, 0, 0, 0);
                    o = __builtin_amdgcn_mfma_f32_16x16x32_bf16(avl[ib], bvh[jb], o, 0, 0, 0);
                    o = __builtin_amdgcn_mfma_f32_16x16x32_bf16(avh[ib], bvl[jb], o, 0, 0, 0);
                    acc[ib][jb] = o;
                }
            __builtin_amdgcn_s_setprio(0);
            __syncthreads();   // drains A-prefetch, frees buf for overwrite
            buf ^= 1;
        }
    }

    const int co0 = cot * 128 + wco * 64;
    const int pxbase = pxt * 128 + wpx * 64;
    #pragma unroll
    for (int ib = 0; ib < 4; ++ib) {
        #pragma unroll
        for (int r = 0; r < 4; ++r) {
            int co = co0 + ib * 16 + qd * 4 + r;
            float bvv = bq[co];
            size_t rowo = ((size_t)(bat * 256 + co)) << 12;
            #pragma unroll
            for (int jb = 0; jb < 4; ++jb) {
                float v = acc[ib][jb][r] + bvv;
                unsigned short h = f2bf(v), l = f2bf(v - bf2f(h));
                size_t o = rowo + pxbase + jb * 16 + ll;
                qH[o] = h; qL[o] = l;
            }
        }
    }
}

// ---------------------------------------------------------------------------
// conv 2x2 s2 p0 via MFMA (k and v), 4-batch half. Grid 128 = 4 bat x 4 sel
// x 8 m-tiles. Block 256 = 4 waves (2co x 2m). fp32 out (pre-GN).
__global__ __launch_bounds__(256, 2) void conv2x2_mfma(
    const unsigned short* __restrict__ yTh, const unsigned short* __restrict__ yTl,
    const unsigned short* __restrict__ wkH, const unsigned short* __restrict__ wkL,
    const unsigned short* __restrict__ wvH, const unsigned short* __restrict__ wvL,
    const float* __restrict__ bk, const float* __restrict__ bv,
    float* __restrict__ kf, float* __restrict__ vf, int b0)
{
    int blk = blockIdx.x;
    int batl = blk & 3;
    int sel = (blk >> 2) & 3;
    int mt  = blk >> 4;                   // 0..7, 128 m each
    int t = threadIdx.x;
    int wv_ = t >> 6;
    int wco = wv_ >> 1, wpx = wv_ & 1;
    int lane = t & 63;
    int ll = lane & 15, qd = lane >> 4;

    const unsigned short* wtH_; const unsigned short* wtL_;
    const float* bias; float* dst; int co0;
    if (sel < 2) { wtH_ = wkH; wtL_ = wkL; bias = bk; dst = kf; co0 = sel * 128 + wco * 64; }
    else         { wtH_ = wvH; wtL_ = wvL; bias = bv; dst = vf; co0 = (sel - 2) * 128 + wco * 64; }

    const unsigned short* aHp[4]; const unsigned short* aLp[4];
    #pragma unroll
    for (int ib = 0; ib < 4; ++ib) {
        size_t o = ((size_t)(co0 + ib * 16 + ll)) * 256 + qd * 8;
        aHp[ib] = wtH_ + o; aLp[ib] = wtL_ + o;
    }
    const unsigned short* bHp[4]; const unsigned short* bLp[4];
    #pragma unroll
    for (int jb = 0; jb < 4; ++jb) {
        int m = mt * 128 + wpx * 64 + jb * 16 + ll;
        int mh = m >> 5, mw = m & 31;
        size_t o = (((size_t)batl << 12) + (size_t)(2 * mh) * 64 + 2 * mw) * 256 + qd * 8;
        bHp[jb] = yTh + o; bLp[jb] = yTl + o;
    }

    f32x4 acc[4][4];
    #pragma unroll
    for (int i = 0; i < 4; ++i)
        #pragma unroll
        for (int j = 0; j < 4; ++j) acc[i][j] = (f32x4){0.f, 0.f, 0.f, 0.f};

    #pragma unroll
    for (int tap = 0; tap < 4; ++tap) {
        const int aoff = tap << 16;
        const int boff = (((tap >> 1) * 64) + (tap & 1)) * 256;
        #pragma unroll 2
        for (int ci0 = 0; ci0 < 256; ci0 += 32) {
            short8 avh[4], avl[4], bvh[4], bvl[4];
            #pragma unroll
            for (int ib = 0; ib < 4; ++ib) {
                avh[ib] = *(const short8*)(aHp[ib] + aoff + ci0);
                avl[ib] = *(const short8*)(aLp[ib] + aoff + ci0);
            }
            #pragma unroll
            for (int jb = 0; jb < 4; ++jb) {
                bvh[jb] = *(const short8*)(bHp[jb] + boff + ci0);
                bvl[jb] = *(const short8*)(bLp[jb] + boff + ci0);
            }
            #pragma unroll
            for (int ib = 0; ib < 4; ++ib)
                #pragma unroll
                for (int jb = 0; jb < 4; ++jb) {
                    f32x4 o = acc[ib][jb];
                    o = __builtin_amdgcn_mfma_f32_16x16x32_bf16(avh[ib], bvh[jb], o, 0, 0, 0);
                    o = __builtin_amdgcn_mfma_f32_16x16x32_bf16(avl[ib], bvh[jb], o, 0, 0, 0);
                    o = __builtin_amdgcn_mfma_f32_16x16x32_bf16(avh[ib], bvl[jb], o, 0, 0, 0);
                    acc[ib][jb] = o;
                }
        }
    }

    const int mbase = mt * 128 + wpx * 64;
    #pragma unroll
    for (int ib = 0; ib < 4; ++ib) {
        #pragma unroll
        for (int r = 0; r < 4; ++r) {
            int co = co0 + ib * 16 + qd * 4 + r;
            float bvv = bias[co];
            float* op = dst + (((size_t)((b0 + batl) * 256 + co)) << 10) + mbase + ll;
            #pragma unroll
            for (int jb = 0; jb < 4; ++jb)
                op[jb * 16] = acc[ib][jb][r] + bvv;
        }
    }
}

// ---------------------------------------------------------------------------
// GroupNorm stats (fp32 input): one block per (batch, group).
__global__ __launch_bounds__(256) void gn_stats_kernel(
    const float* __restrict__ buf, float* __restrict__ stats, int S)
{
    int bg = blockIdx.x;
    const float4* p = (const float4*)(buf + (size_t)bg * 8 * S);
    int n4 = 2 * S;
    float s = 0.f, s2 = 0.f;
    for (int i = threadIdx.x; i < n4; i += 256) {
        float4 vv = p[i];
        s  += vv.x + vv.y + vv.z + vv.w;
        s2 += vv.x * vv.x + vv.y * vv.y + vv.z * vv.z + vv.w * vv.w;
    }
    for (int d = 1; d < 64; d <<= 1) { s += __shfl_xor(s, d); s2 += __shfl_xor(s2, d); }
    __shared__ float red[8];
    int w = threadIdx.x >> 6;
    if ((threadIdx.x & 63) == 0) { red[w] = s; red[w + 4] = s2; }
    __syncthreads();
    if (threadIdx.x == 0) {
        s  = red[0] + red[1] + red[2] + red[3];
        s2 = red[4] + red[5] + red[6] + red[7];
        float invn = 1.f / (float)(8 * S);
        float mean = s * invn;
        float var = s2 * invn - mean * mean;
        if (var < 0.f) var = 0.f;
        stats[bg * 2]     = mean;
        stats[bg * 2 + 1] = 1.f / sqrtf(var + 1e-5f);
    }
}

// GroupNorm stats from bf16 hi/lo pair (q path).
__global__ __launch_bounds__(256) void gn_stats_pair(
    const unsigned short* __restrict__ hi, const unsigned short* __restrict__ lo,
    float* __restrict__ stats, int S)
{
    int bg = blockIdx.x;
    const uint4* ph = (const uint4*)(hi + (size_t)bg * 8 * S);
    const uint4* pl = (const uint4*)(lo + (size_t)bg * 8 * S);
    int n8 = S;
    float s = 0.f, s2 = 0.f;
    for (int i = threadIdx.x; i < n8; i += 256) {
        uint4 a = ph[i], b2 = pl[i];
        unsigned ua[4] = {a.x, a.y, a.z, a.w}, ub[4] = {b2.x, b2.y, b2.z, b2.w};
        #pragma unroll
        for (int j = 0; j < 4; ++j) {
            float x0 = __uint_as_float(ua[j] << 16) + __uint_as_float(ub[j] << 16);
            float x1 = __uint_as_float(ua[j] & 0xffff0000u) + __uint_as_float(ub[j] & 0xffff0000u);
            s += x0 + x1;
            s2 += x0 * x0 + x1 * x1;
        }
    }
    for (int d = 1; d < 64; d <<= 1) { s += __shfl_xor(s, d); s2 += __shfl_xor(s2, d); }
    __shared__ float red[8];
    int w = threadIdx.x >> 6;
    if ((threadIdx.x & 63) == 0) { red[w] = s; red[w + 4] = s2; }
    __syncthreads();
    if (threadIdx.x == 0) {
        s  = red[0] + red[1] + red[2] + red[3];
        s2 = red[4] + red[5] + red[6] + red[7];
        float invn = 1.f / (float)(8 * S);
        float mean = s * invn;
        float var = s2 * invn - mean * mean;
        if (var < 0.f) var = 0.f;
        stats[bg * 2]     = mean;
        stats[bg * 2 + 1] = 1.f / sqrtf(var + 1e-5f);
    }
}

// GN + affine + SiLU (+extra scale) on bf16 pair, in place (q path, N=4096).
__global__ __launch_bounds__(256) void gn_silu_pair(
    unsigned short* __restrict__ hi, unsigned short* __restrict__ lo,
    const float* __restrict__ stats, const float* __restrict__ scale,
    const float* __restrict__ bias, float extra, int total8)
{
    int idx = blockIdx.x * 256 + threadIdx.x;
    if (idx >= total8) return;
    size_t e = (size_t)idx * 8;
    int c  = (int)((e >> 12) & 255);
    int gg = (int)(e >> 15);
    float mean = stats[gg * 2], rstd = stats[gg * 2 + 1];
    float a  = scale[c] * rstd;
    float bb = bias[c] - mean * a;
    uint4 uh = ((uint4*)hi)[idx], ul = ((uint4*)lo)[idx];
    unsigned ha[4] = {uh.x, uh.y, uh.z, uh.w}, la[4] = {ul.x, ul.y, ul.z, ul.w};
    unsigned oh[4], ol[4];
    #pragma unroll
    for (int j = 0; j < 4; ++j) {
        float x0 = __uint_as_float(ha[j] << 16) + __uint_as_float(la[j] << 16);
        float x1 = __uint_as_float(ha[j] & 0xffff0000u) + __uint_as_float(la[j] & 0xffff0000u);
        float y0 = x0 * a + bb, y1 = x1 * a + bb;
        float s0 = extra * y0 / (1.f + __expf(-y0));
        float s1 = extra * y1 / (1.f + __expf(-y1));
        unsigned short h0 = f2bf(s0), l0 = f2bf(s0 - bf2f(h0));
        unsigned short h1 = f2bf(s1), l1 = f2bf(s1 - bf2f(h1));
        oh[j] = h0 | ((unsigned)h1 << 16);
        ol[j] = l0 | ((unsigned)l1 << 16);
    }
    ((uint4*)hi)[idx] = make_uint4(oh[0], oh[1], oh[2], oh[3]);
    ((uint4*)lo)[idx] = make_uint4(ol[0], ol[1], ol[2], ol[3]);
}

// GN + affine + SiLU on fp32 v -> bf16 hi/lo pair, natural [C][M] layout.
__global__ __launch_bounds__(256) void gn_silu_split_v(
    const float* __restrict__ vf, unsigned short* __restrict__ hi,
    unsigned short* __restrict__ lo, const float* __restrict__ stats,
    const float* __restrict__ scale, const float* __restrict__ bias, int total8)
{
    int idx = blockIdx.x * 256 + threadIdx.x;
    if (idx >= total8) return;
    size_t e = (size_t)idx * 8;
    int c  = (int)((e >> 10) & 255);
    int gg = (int)(e >> 13);
    float mean = stats[gg * 2], rstd = stats[gg * 2 + 1];
    float a  = scale[c] * rstd;
    float bb = bias[c] - mean * a;
    float4 f0 = ((const float4*)vf)[idx * 2];
    float4 f1 = ((const float4*)vf)[idx * 2 + 1];
    float xs[8] = {f0.x, f0.y, f0.z, f0.w, f1.x, f1.y, f1.z, f1.w};
    unsigned oh[4], ol[4];
    #pragma unroll
    for (int j = 0; j < 4; ++j) {
        float y0 = xs[2 * j] * a + bb, y1 = xs[2 * j + 1] * a + bb;
        float s0 = y0 / (1.f + __expf(-y0));
        float s1 = y1 / (1.f + __expf(-y1));
        unsigned short h0 = f2bf(s0), l0 = f2bf(s0 - bf2f(h0));
        unsigned short h1 = f2bf(s1), l1 = f2bf(s1 - bf2f(h1));
        oh[j] = h0 | ((unsigned)h1 << 16);
        ol[j] = l0 | ((unsigned)l1 << 16);
    }
    ((uint4*)hi)[idx] = make_uint4(oh[0], oh[1], oh[2], oh[3]);
    ((uint4*)lo)[idx] = make_uint4(ol[0], ol[1], ol[2], ol[3]);
}

// GN + affine + SiLU on fp32 k -> TRANSPOSED bf16 hi/lo [B][M][C] (B-frag layout).
__global__ __launch_bounds__(256) void gn_silu_split_kT(
    const float* __restrict__ kf, unsigned short* __restrict__ th,
    unsigned short* __restrict__ tl, const float* __restrict__ stats,
    const float* __restrict__ scale, const float* __restrict__ bias)
{
    int bm = blockIdx.x;              // 8 batches * 128 m8-groups
    int b = bm >> 7, m8 = (bm & 127) * 8;
    int c = threadIdx.x;
    int gg = b * 32 + (c >> 3);
    float mean = stats[gg * 2], rstd = stats[gg * 2 + 1];
    float a  = scale[c] * rstd;
    float bb = bias[c] - mean * a;
    const float* src = kf + (((size_t)(b * 256 + c)) << 10) + m8;
    float4 f0 = *(const float4*)src;
    float4 f1 = *(const float4*)(src + 4);
    float xs[8] = {f0.x, f0.y, f0.z, f0.w, f1.x, f1.y, f1.z, f1.w};
    #pragma unroll
    for (int j = 0; j < 8; ++j) {
        float y = xs[j] * a + bb;
        float s = y / (1.f + __expf(-y));
        unsigned short h = f2bf(s), l = f2bf(s - bf2f(h));
        size_t o = ((size_t)b * M_ + m8 + j) * C_ + c;
        th[o] = h;
        tl[o] = l;
    }
}

// ---------------------------------------------------------------------------
// Fused flash attention, split-bf16 MFMA, LDS-STAGED K/V pipeline.
// Grid 512 = 8 bat x 64 nt (64 q-rows). Block 256 = 4 q-waves (16 rows each),
// all sharing the same m-tile stream (32 m per tile, 32 tiles).
__global__ __launch_bounds__(256, 2) void attn_mfma(
    const unsigned short* __restrict__ qh, const unsigned short* __restrict__ qlo,
    const unsigned short* __restrict__ kth, const unsigned short* __restrict__ ktl,
    const unsigned short* __restrict__ vh, const unsigned short* __restrict__ vlo,
    const float* __restrict__ gamma, float* __restrict__ out)
{
    __shared__ __align__(16) unsigned short kldsH[32 * 256];   // 16KB [m][Cg^ (m&7)]
    __shared__ __align__(16) unsigned short kldsL[32 * 256];
    __shared__ __align__(16) unsigned short vldsH[256 * 32];   // 16KB [c][g ^ (c&3)]
    __shared__ __align__(16) unsigned short vldsL[256 * 32];
    __shared__ __align__(16) unsigned short pH[4][16][40];
    __shared__ __align__(16) unsigned short pL[4][16][40];
    __shared__ float alphaS[4][16];

    int blk = blockIdx.x;
    int bat = blk & 7;
    int nt  = blk >> 3;           // 0..63
    int t = threadIdx.x;
    int w = t >> 6;               // q-wave 0..3
    int lane = t & 63;
    int ll = lane & 15;
    int qd = lane >> 4;
    int n0 = nt * 64 + w * 16;

    short8 aqh[8], aql[8];
    {
        const unsigned short* qb1 = qh  + (size_t)bat * C_ * N_ + n0 + ll;
        const unsigned short* qb2 = qlo + (size_t)bat * C_ * N_ + n0 + ll;
        #pragma unroll
        for (int ks = 0; ks < 8; ++ks) {
            #pragma unroll
            for (int j = 0; j < 8; ++j) {
                size_t off = (size_t)(ks * 32 + qd * 8 + j) * N_;
                aqh[ks][j] = (short)qb1[off];
                aql[ks][j] = (short)qb2[off];
            }
        }
    }

    f32x4 oacc[16];
    #pragma unroll
    for (int i = 0; i < 16; ++i) oacc[i] = (f32x4){0.f, 0.f, 0.f, 0.f};
    f32x4 lacc = (f32x4){0.f, 0.f, 0.f, 0.f};
    float mrun[4] = {-3e38f, -3e38f, -3e38f, -3e38f};
    const short8 ones = (short8){16256, 16256, 16256, 16256, 16256, 16256, 16256, 16256};

    const unsigned short* kg = ((w & 1) == 0 ? kth : ktl) + (size_t)bat * M_ * C_;
    const unsigned short* vg = ((w & 1) == 0 ? vh  : vlo) + (size_t)bat * C_ * M_;
    unsigned short* kdst = (w & 1) ? kldsL : kldsH;
    unsigned short* vdst = (w & 1) ? vldsL : vldsH;
    const int krow  = lane >> 5;
    const int kcolg = lane & 31;
    const int vc_l  = lane >> 2;
    const int vg_g  = lane & 3;

    for (int mt = 0; mt < 32; ++mt) {
        const int m0 = mt * 32;
        if (w < 2) {
            #pragma unroll
            for (int i = 0; i < 16; ++i) {
                int row = 2 * i + krow;
                const unsigned short* src = kg + (size_t)(m0 + row) * 256
                                            + ((kcolg ^ (row & 7)) << 3);
                gl_lds16(src, kdst + i * 512);
            }
        } else {
            #pragma unroll
            for (int i = 0; i < 16; ++i) {
                int c = i * 16 + vc_l;
                const unsigned short* src = vg + (size_t)c * M_ + m0
                                            + ((vg_g ^ (c & 3)) << 3);
                gl_lds16(src, vdst + i * 512);
            }
        }
        __syncthreads();

        f32x4 s0 = {0.f, 0.f, 0.f, 0.f}, s1 = {0.f, 0.f, 0.f, 0.f};
        __builtin_amdgcn_s_setprio(1);
        #pragma unroll
        for (int ks = 0; ks < 8; ++ks) {
            int cg = ks * 4 + qd;
            int a0 = ll * 256 + ((cg ^ (ll & 7)) << 3);
            int a1 = (ll + 16) * 256 + ((cg ^ (ll & 7)) << 3);
            short8 b0h = *(const short8*)&kldsH[a0];
            short8 b1h = *(const short8*)&kldsH[a1];
            short8 b0l = *(const short8*)&kldsL[a0];
            short8 b1l = *(const short8*)&kldsL[a1];
            s0 = __builtin_amdgcn_mfma_f32_16x16x32_bf16(aqh[ks], b0h, s0, 0, 0, 0);
            s1 = __builtin_amdgcn_mfma_f32_16x16x32_bf16(aqh[ks], b1h, s1, 0, 0, 0);
            s0 = __builtin_amdgcn_mfma_f32_16x16x32_bf16(aql[ks], b0h, s0, 0, 0, 0);
            s1 = __builtin_amdgcn_mfma_f32_16x16x32_bf16(aql[ks], b1h, s1, 0, 0, 0);
            s0 = __builtin_amdgcn_mfma_f32_16x16x32_bf16(aqh[ks], b0l, s0, 0, 0, 0);
            s1 = __builtin_amdgcn_mfma_f32_16x16x32_bf16(aqh[ks], b1l, s1, 0, 0, 0);
        }
        __builtin_amdgcn_s_setprio(0);

        float alpha4[4];
        #pragma unroll
        for (int r = 0; r < 4; ++r) {
            float mx = fmaxf(s0[r], s1[r]);
            mx = fmaxf(mx, __shfl_xor(mx, 1));
            mx = fmaxf(mx, __shfl_xor(mx, 2));
            mx = fmaxf(mx, __shfl_xor(mx, 4));
            mx = fmaxf(mx, __shfl_xor(mx, 8));
            float mn = fmaxf(mrun[r], mx);
            float al = __expf(mrun[r] - mn);
            mrun[r] = mn;
            float p0 = __expf(s0[r] - mn);
            float p1 = __expf(s1[r] - mn);
            alpha4[r] = al;
            unsigned short h0 = f2bf(p0), l0 = f2bf(p0 - bf2f(h0));
            unsigned short h1 = f2bf(p1), l1 = f2bf(p1 - bf2f(h1));
            int rn = qd * 4 + r;
            pH[w][rn][ll] = h0;  pH[w][rn][16 + ll] = h1;
            pL[w][rn][ll] = l0;  pL[w][rn][16 + ll] = l1;
        }
        if (ll == 0) {
            #pragma unroll
            for (int r = 0; r < 4; ++r) alphaS[w][qd * 4 + r] = alpha4[r];
        }
        __builtin_amdgcn_wave_barrier();
        short8 bph = *(const short8*)&pH[w][ll][qd * 8];
        short8 bpl = *(const short8*)&pL[w][ll][qd * 8];
        float an = alphaS[w][ll];
        {
            f32x4 o = lacc;
            o[0] *= an; o[1] *= an; o[2] *= an; o[3] *= an;
            o = __builtin_amdgcn_mfma_f32_16x16x32_bf16(ones, bph, o, 0, 0, 0);
            o = __builtin_amdgcn_mfma_f32_16x16x32_bf16(ones, bpl, o, 0, 0, 0);
            lacc = o;
        }
        __builtin_amdgcn_s_setprio(1);
        #pragma unroll
        for (int ct = 0; ct < 16; ++ct) {
            int c = ct * 16 + ll;
            int av = c * 32 + ((qd ^ (c & 3)) << 3);
            short8 avh = *(const short8*)&vldsH[av];
            short8 avl = *(const short8*)&vldsL[av];
            f32x4 o = oacc[ct];
            o[0] *= an; o[1] *= an; o[2] *= an; o[3] *= an;
            o = __builtin_amdgcn_mfma_f32_16x16x32_bf16(avh, bph, o, 0, 0, 0);
            o = __builtin_amdgcn_mfma_f32_16x16x32_bf16(avl, bph, o, 0, 0, 0);
            o = __builtin_amdgcn_mfma_f32_16x16x32_bf16(avh, bpl, o, 0, 0, 0);
            oacc[ct] = o;
        }
        __builtin_amdgcn_s_setprio(0);
        __syncthreads();
    }

    float linv = gamma[0] / lacc[0];
    float* ob = out + (size_t)bat * C_ * N_ + n0 + ll;
    #pragma unroll
    for (int ct = 0; ct < 16; ++ct) {
        #pragma unroll
        for (int r = 0; r < 4; ++r) {
            int c = ct * 16 + qd * 4 + r;
            ob[(size_t)c * N_] = oacc[ct][r] * linv;
        }
    }
}

// ---------------------------------------------------------------------------
extern "C" void kernel_launch(void* const* d_in, const int* in_sizes, int n_in,
                              void* d_out, int out_size, void* d_ws, size_t ws_size,
                              hipStream_t stream)
{
    const float* x   = (const float*)d_in[0];
    const float* y   = (const float*)d_in[1];
    const float* Wq  = (const float*)d_in[2];
    const float* bq  = (const float*)d_in[3];
    const float* gqs = (const float*)d_in[4];
    const float* gqb = (const float*)d_in[5];
    const float* Wk  = (const float*)d_in[6];
    const float* bk  = (const float*)d_in[7];
    const float* gks = (const float*)d_in[8];
    const float* gkb = (const float*)d_in[9];
    const float* Wv  = (const float*)d_in[10];
    const float* bv  = (const float*)d_in[11];
    const float* gvs = (const float*)d_in[12];
    const float* gvb = (const float*)d_in[13];
    const float* gamma = (const float*)d_in[14];
    float* out = (float*)d_out;

    // ws layout (71.6 MB total, all phases):
    //   qH, qL: 2 x 16.78 MB
    //   regA (phase-overlaid, 38.05 MB):
    //     conv3 phase:  xpH,xpL [8][66][66][256] bf16 + wtH,wtL       (38.05 MB)
    //     conv2 phase:  kf,vf fp32 (16.78) | yT half-batch (16.78) | w2 (2.10)
    //     gn/attn:      kf,vf | kTh,kTl,vH,vL | stats                 (33.57 MB)
    char* base = (char*)d_ws;
    unsigned short* qH = (unsigned short*)base;
    unsigned short* qL = qH + 8388608;
    char* regA = (char*)(qL + 8388608);
    // conv3 overlay
    unsigned short* xpH = (unsigned short*)regA;      // 8,921,088 shorts
    unsigned short* xpL = xpH + 8921088;
    unsigned short* wtH = xpL + 8921088;              // 589,824 shorts
    unsigned short* wtL = wtH + 589824;
    // pipeline overlay
    float* kf = (float*)regA;                         // 2,097,152 floats
    float* vf = kf + 2097152;
    unsigned short* kTh = (unsigned short*)(vf + 2097152);
    unsigned short* kTl = kTh + 2097152;
    unsigned short* vH  = kTl + 2097152;
    unsigned short* vL  = vH + 2097152;
    float* stq = (float*)(vL + 2097152);
    float* stk = stq + 512;
    float* stv = stk + 512;
    // conv2 overlay (after kf,vf; dead once conv2x2_mfma finishes)
    unsigned short* yTh  = (unsigned short*)(vf + 2097152);   // 4,194,304 shorts (4 bat)
    unsigned short* yTl  = yTh + 4194304;
    unsigned short* w2kH = yTl + 4194304;                     // 262,144 shorts each
    unsigned short* w2kL = w2kH + 262144;
    unsigned short* w2vH = w2kL + 262144;
    unsigned short* w2vL = w2vH + 262144;

    // conv3x3 (q path) via MFMA (LDS-staged operands)
    hipMemsetAsync(xpH, 0, (size_t)2 * 8921088 * sizeof(unsigned short), stream);
    split_w_tap<<<256, 256, 0, stream>>>(Wq, wtH, wtL);
    split_x_pad<<<512, 256, 0, stream>>>(x, xpH, xpL);
    conv3x3_mfma<<<512, 256, 0, stream>>>(xpH, xpL, wtH, wtL, bq, qH, qL);

    // conv2x2 (k,v) via MFMA, two 4-batch halves (fits 71.6 MB workspace).
    split_w2<<<256, 256, 0, stream>>>(Wk, w2kH, w2kL);
    split_w2<<<256, 256, 0, stream>>>(Wv, w2vH, w2vL);
    split_y_t<<<256, 256, 0, stream>>>(y, yTh, yTl, 0);
    conv2x2_mfma<<<128, 256, 0, stream>>>(yTh, yTl, w2kH, w2kL, w2vH, w2vL,
                                          bk, bv, kf, vf, 0);
    split_y_t<<<256, 256, 0, stream>>>(y, yTh, yTl, 4);
    conv2x2_mfma<<<128, 256, 0, stream>>>(yTh, yTl, w2kH, w2kL, w2vH, w2vL,
                                          bk, bv, kf, vf, 4);

    gn_stats_pair<<<256, 256, 0, stream>>>(qH, qL, stq, 4096);
    gn_stats_kernel<<<256, 256, 0, stream>>>(kf, stk, 1024);
    gn_stats_kernel<<<256, 256, 0, stream>>>(vf, stv, 1024);
    gn_silu_pair<<<4096, 256, 0, stream>>>(qH, qL, stq, gqs, gqb, 0.0625f, 1048576);
    gn_silu_split_v<<<1024, 256, 0, stream>>>(vf, vH, vL, stv, gvs, gvb, 262144);
    gn_silu_split_kT<<<1024, 256, 0, stream>>>(kf, kTh, kTl, stk, gks, gkb);
    attn_mfma<<<512, 256, 0, stream>>>(qH, qL, kTh, kTl, vH, vL, gamma, out);
}

// Round 8
// 505.820 us; speedup vs baseline: 2.4074x; 1.1061x over previous
//
#include <hip/hip_runtime.h>
#include <hip/hip_bf16.h>
#include <math.h>

#define B_ 8
#define C_ 256
#define H_ 64
#define W_ 64
#define N_ 4096
#define M_ 1024
#define HW_ 4096

typedef __attribute__((ext_vector_type(8))) short short8;
typedef __attribute__((ext_vector_type(4))) float f32x4;

__device__ __forceinline__ unsigned short f2bf(float x) {
    unsigned u = __float_as_uint(x);
    u += 0x7fffu + ((u >> 16) & 1u);          // round-to-nearest-even
    return (unsigned short)(u >> 16);
}
__device__ __forceinline__ float bf2f(unsigned short h) {
    return __uint_as_float(((unsigned)h) << 16);
}

// 16B async global->LDS (no VGPR round-trip). lds base wave-uniform; dest = base + lane*16.
__device__ __forceinline__ void gl_lds16(const unsigned short* g, unsigned short* l) {
    __builtin_amdgcn_global_load_lds(
        (const __attribute__((address_space(1))) unsigned int*)g,
        (__attribute__((address_space(3))) unsigned int*)l, 16, 0, 0);
}

// ---------------------------------------------------------------------------
// Split Wq [256co][256ci][3][3] fp32 -> per-tap bf16 hi/lo [9][256co][256ci].
__global__ __launch_bounds__(256) void split_w_tap(
    const float* __restrict__ Wq, unsigned short* __restrict__ wtH,
    unsigned short* __restrict__ wtL)
{
    int co = blockIdx.x, ci = threadIdx.x;
    const float* wp = Wq + ((size_t)co * 256 + ci) * 9;
    #pragma unroll
    for (int tap = 0; tap < 9; ++tap) {
        float v = wp[tap];
        unsigned short h = f2bf(v), l = f2bf(v - bf2f(h));
        size_t o = ((size_t)tap << 16) + ((size_t)co << 8) + ci;
        wtH[o] = h; wtL[o] = l;
    }
}

// Split W [256co][256ci][2][2] fp32 -> per-tap bf16 hi/lo [4][256co][256ci].
__global__ __launch_bounds__(256) void split_w2(
    const float* __restrict__ Wsrc, unsigned short* __restrict__ wH,
    unsigned short* __restrict__ wL)
{
    int co = blockIdx.x, ci = threadIdx.x;
    const float* wp = Wsrc + ((size_t)co * 256 + ci) * 4;
    #pragma unroll
    for (int tap = 0; tap < 4; ++tap) {
        float v = wp[tap];
        unsigned short h = f2bf(v), l = f2bf(v - bf2f(h));
        size_t o = ((size_t)tap << 16) + ((size_t)co << 8) + ci;
        wH[o] = h; wL[o] = l;
    }
}

// ---------------------------------------------------------------------------
// Transpose+split x [8][256][64][64] fp32 -> padded NHWC bf16 hi/lo
// [8][66][66][256] (halo pre-zeroed by memset). LDS-tiled transpose.
__global__ __launch_bounds__(256) void split_x_pad(
    const float* __restrict__ x, unsigned short* __restrict__ xpH,
    unsigned short* __restrict__ xpL)
{
    __shared__ float tile[64][65];
    int blk = blockIdx.x;            // b*64 + h
    int b = blk >> 6, h = blk & 63;
    int t = threadIdx.x;
    const float* xb = x + ((size_t)b << 20) + (size_t)h * 64;
    size_t obase = (((size_t)b * 4356) + (size_t)(h + 1) * 66 + 1) * 256;
    unsigned short* oH = xpH + obase;
    unsigned short* oL = xpL + obase;
    for (int cc = 0; cc < 256; cc += 64) {
        int wi = t & 63, cq = t >> 6;
        #pragma unroll
        for (int r = 0; r < 16; ++r) {
            int cl = cq * 16 + r;
            tile[cl][wi] = xb[((size_t)(cc + cl)) * 4096 + wi];
        }
        __syncthreads();
        int cl = t & 63, wq = t >> 6;
        #pragma unroll
        for (int r = 0; r < 16; ++r) {
            int wwi = wq * 16 + r;
            float v = tile[cl][wwi];
            unsigned short hh = f2bf(v), lo = f2bf(v - bf2f(hh));
            size_t o = (size_t)wwi * 256 + cc + cl;
            oH[o] = hh; oL[o] = lo;
        }
        __syncthreads();
    }
}

// Transpose+split y (4-batch half) fp32 -> NHWC bf16 hi/lo [4][64][64][256].
__global__ __launch_bounds__(256) void split_y_t(
    const float* __restrict__ y, unsigned short* __restrict__ yTh,
    unsigned short* __restrict__ yTl, int b0)
{
    __shared__ float tile[64][65];
    int blk = blockIdx.x;            // bl*64 + h, bl in [0,4)
    int bl = blk >> 6, h = blk & 63;
    int t = threadIdx.x;
    const float* yb = y + ((size_t)(b0 + bl) << 20) + (size_t)h * 64;
    size_t obase = (((size_t)bl << 12) + (size_t)h * 64) * 256;
    unsigned short* oH = yTh + obase;
    unsigned short* oL = yTl + obase;
    for (int cc = 0; cc < 256; cc += 64) {
        int wi = t & 63, cq = t >> 6;
        #pragma unroll
        for (int r = 0; r < 16; ++r) {
            int cl = cq * 16 + r;
            tile[cl][wi] = yb[((size_t)(cc + cl)) * 4096 + wi];
        }
        __syncthreads();
        int cl = t & 63, wq = t >> 6;
        #pragma unroll
        for (int r = 0; r < 16; ++r) {
            int wwi = wq * 16 + r;
            float v = tile[cl][wwi];
            unsigned short hh = f2bf(v), lo = f2bf(v - bf2f(hh));
            size_t o = (size_t)wwi * 256 + cc + cl;
            oH[o] = hh; oL[o] = lo;
        }
        __syncthreads();
    }
}

// ---------------------------------------------------------------------------
// conv 3x3 s1 p1 via MFMA, LDS-STAGED operands (R7-verified).
__global__ __launch_bounds__(256, 2) void conv3x3_mfma(
    const unsigned short* __restrict__ xpH, const unsigned short* __restrict__ xpL,
    const unsigned short* __restrict__ wtH, const unsigned short* __restrict__ wtL,
    const float* __restrict__ bq,
    unsigned short* __restrict__ qH, unsigned short* __restrict__ qL)
{
    __shared__ __align__(16) unsigned short bldsH[272 * 32];   // 17.4KB x-tile hi
    __shared__ __align__(16) unsigned short bldsL[272 * 32];   // (264 cells + pad)
    __shared__ __align__(16) unsigned short aldsH[2][128 * 32]; // 8KB/buf weights hi
    __shared__ __align__(16) unsigned short aldsL[2][128 * 32];

    int blk = blockIdx.x;
    int bat = blk & 7;
    int rest = blk >> 3;
    int cot = rest & 1;
    int pxt = rest >> 1;                  // 32 tiles of 128 px (2 rows of 64)
    int t = threadIdx.x;
    int w = t >> 6;
    int wco = w >> 1, wpx = w & 1;
    int lane = t & 63;
    int ll = lane & 15, qd = lane >> 4;
    const int h0 = pxt * 2;               // padded-coords row base
    const int co0b = cot * 128;

    const unsigned short* xpHb = xpH + (size_t)bat * 4356 * 256;
    const unsigned short* xpLb = xpL + (size_t)bat * 4356 * 256;

    f32x4 acc[4][4];
    #pragma unroll
    for (int i = 0; i < 4; ++i)
        #pragma unroll
        for (int j = 0; j < 4; ++j) acc[i][j] = (f32x4){0.f, 0.f, 0.f, 0.f};

    int buf = 0;
    for (int chunk = 0; chunk < 8; ++chunk) {
        const int ci0 = chunk * 32;
        // ---- stage B x-tile: rows h0..h0+3, cols 0..65, 32 ci (hi+lo)
        for (int j = w; j < 34; j += 4) {
            int half = (j >= 17);
            int jj = half ? j - 17 : j;
            int gid = jj * 64 + lane;                 // 0..1087
            int cell = gid >> 2;
            int g = gid & 3;
            int cellc = cell < 264 ? cell : 263;      // clamp pad cells
            int dr = cellc / 66;
            int cc = cellc - dr * 66;
            const unsigned short* src = (half ? xpLb : xpHb)
                + (((size_t)(h0 + dr) * 66 + cc) << 8) + ci0
                + ((g ^ (cellc & 3)) << 3);
            unsigned short* dst = (half ? bldsL : bldsH) + jj * 512;
            gl_lds16(src, dst);
        }
        // ---- stage A weights, tap 0 -> buf
        for (int j = w; j < 16; j += 4) {
            int half = j >> 3;
            int jj = j & 7;
            int gid = jj * 64 + lane;                 // 0..511
            int co = gid >> 2;
            int g = gid & 3;
            const unsigned short* src = (half ? wtL : wtH)
                + (((size_t)(co0b + co)) << 8) + ci0 + ((g ^ (co & 3)) << 3);
            unsigned short* dst = (half ? aldsL[buf] : aldsH[buf]) + jj * 512;
            gl_lds16(src, dst);
        }
        __syncthreads();

        for (int tap = 0; tap < 9; ++tap) {
            // prefetch A for next tap into the other buffer (lands by barrier)
            if (tap < 8) {
                const int aoff = (tap + 1) << 16;
                for (int j = w; j < 16; j += 4) {
                    int half = j >> 3;
                    int jj = j & 7;
                    int gid = jj * 64 + lane;
                    int co = gid >> 2;
                    int g = gid & 3;
                    const unsigned short* src = (half ? wtL : wtH)
                        + aoff + (((size_t)(co0b + co)) << 8) + ci0
                        + ((g ^ (co & 3)) << 3);
                    unsigned short* dst = (half ? aldsL[buf ^ 1] : aldsH[buf ^ 1]) + jj * 512;
                    gl_lds16(src, dst);
                }
            }
            int kh = tap / 3, kw = tap - kh * 3;
            short8 avh[4], avl[4], bvh[4], bvl[4];
            #pragma unroll
            for (int ib = 0; ib < 4; ++ib) {
                int col = wco * 64 + ib * 16 + ll;
                int aa = col * 32 + ((qd ^ (col & 3)) << 3);
                avh[ib] = *(const short8*)&aldsH[buf][aa];
                avl[ib] = *(const short8*)&aldsL[buf][aa];
            }
            #pragma unroll
            for (int jb = 0; jb < 4; ++jb) {
                int cell = (wpx + kh) * 66 + jb * 16 + ll + kw;
                int ba = cell * 32 + ((qd ^ (cell & 3)) << 3);
                bvh[jb] = *(const short8*)&bldsH[ba];
                bvl[jb] = *(const short8*)&bldsL[ba];
            }
            __builtin_amdgcn_s_setprio(1);
            #pragma unroll
            for (int ib = 0; ib < 4; ++ib)
                #pragma unroll
                for (int jb = 0; jb < 4; ++jb) {
                    f32x4 o = acc[ib][jb];
                    o = __builtin_amdgcn_mfma_f32_16x16x32_bf16(avh[ib], bvh[jb], o, 0, 0, 0);
                    o = __builtin_amdgcn_mfma_f32_16x16x32_bf16(avl[ib], bvh[jb], o, 0, 0, 0);
                    o = __builtin_amdgcn_mfma_f32_16x16x32_bf16(avh[ib], bvl[jb], o, 0, 0, 0);
                    acc[ib][jb] = o;
                }
            __builtin_amdgcn_s_setprio(0);
            __syncthreads();   // drains A-prefetch, frees buf for overwrite
            buf ^= 1;
        }
    }

    const int co0 = cot * 128 + wco * 64;
    const int pxbase = pxt * 128 + wpx * 64;
    #pragma unroll
    for (int ib = 0; ib < 4; ++ib) {
        #pragma unroll
        for (int r = 0; r < 4; ++r) {
            int co = co0 + ib * 16 + qd * 4 + r;
            float bvv = bq[co];
            size_t rowo = ((size_t)(bat * 256 + co)) << 12;
            #pragma unroll
            for (int jb = 0; jb < 4; ++jb) {
                float v = acc[ib][jb][r] + bvv;
                unsigned short h = f2bf(v), l = f2bf(v - bf2f(h));
                size_t o = rowo + pxbase + jb * 16 + ll;
                qH[o] = h; qL[o] = l;
            }
        }
    }
}

// ---------------------------------------------------------------------------
// conv 2x2 s2 p0 via MFMA (k and v), 4-batch half, LDS-STAGED B operand.
// Grid 128 = 4 bat x 4 sel x 8 m-tiles. Block 256 = 4 waves (2co x 2m).
// Per ci-chunk(32): stage full y input patch [8 rows][64 w][32ci] hi+lo
// (64KB, swizzle pi=(cell>>1)&3) via global_load_lds; A direct from L2.
__global__ __launch_bounds__(256, 2) void conv2x2_mfma(
    const unsigned short* __restrict__ yTh, const unsigned short* __restrict__ yTl,
    const unsigned short* __restrict__ wkH, const unsigned short* __restrict__ wkL,
    const unsigned short* __restrict__ wvH, const unsigned short* __restrict__ wvL,
    const float* __restrict__ bk, const float* __restrict__ bv,
    float* __restrict__ kf, float* __restrict__ vf, int b0)
{
    __shared__ __align__(16) unsigned short bldsH[512 * 32];   // 32KB patch hi
    __shared__ __align__(16) unsigned short bldsL[512 * 32];   // 32KB patch lo

    int blk = blockIdx.x;
    int batl = blk & 3;
    int sel = (blk >> 2) & 3;
    int mt  = blk >> 4;                   // 0..7, 128 m each
    int t = threadIdx.x;
    int w = t >> 6;
    int wco = w >> 1, wpx = w & 1;
    int lane = t & 63;
    int ll = lane & 15, qd = lane >> 4;

    const unsigned short* wtH_; const unsigned short* wtL_;
    const float* bias; float* dst; int co0;
    if (sel < 2) { wtH_ = wkH; wtL_ = wkL; bias = bk; dst = kf; co0 = sel * 128 + wco * 64; }
    else         { wtH_ = wvH; wtL_ = wvL; bias = bv; dst = vf; co0 = (sel - 2) * 128 + wco * 64; }

    const unsigned short* aHp[4]; const unsigned short* aLp[4];
    #pragma unroll
    for (int ib = 0; ib < 4; ++ib) {
        size_t o = ((size_t)(co0 + ib * 16 + ll)) * 256 + qd * 8;
        aHp[ib] = wtH_ + o; aLp[ib] = wtL_ + o;
    }
    // staging bases: pixel index within batch = 8*mt*64 + cell (cell = pr*64+wc)
    const unsigned short* ySH = yTh + ((((size_t)batl << 12) + mt * 512) << 8);
    const unsigned short* ySL = yTl + ((((size_t)batl << 12) + mt * 512) << 8);
    const int half_ = w >> 1;             // waves 0,1: hi; waves 2,3: lo
    const int gi0 = (w & 1) * 16;
    const unsigned short* yS = half_ ? ySL : ySH;
    unsigned short* bd = half_ ? bldsL : bldsH;
    const int scell = lane >> 2;          // cell within instr
    const int sg = lane & 3;              // granule

    f32x4 acc[4][4];
    #pragma unroll
    for (int i = 0; i < 4; ++i)
        #pragma unroll
        for (int j = 0; j < 4; ++j) acc[i][j] = (f32x4){0.f, 0.f, 0.f, 0.f};

    for (int chunk = 0; chunk < 8; ++chunk) {
        const int ci0 = chunk * 32;
        // ---- stage B patch (64 instrs of 1KB across 4 waves)
        #pragma unroll
        for (int j = 0; j < 16; ++j) {
            int gi = gi0 + j;
            int cell = gi * 16 + scell;
            const unsigned short* src = yS + ((size_t)cell << 8) + ci0
                                        + ((sg ^ ((cell >> 1) & 3)) << 3);
            gl_lds16(src, bd + gi * 512);
        }
        __syncthreads();

        #pragma unroll
        for (int tap = 0; tap < 4; ++tap) {
            int kh = tap >> 1, kw = tap & 1;
            const int aoff = (tap << 16) + ci0;
            short8 avh[4], avl[4], bvh[4], bvl[4];
            #pragma unroll
            for (int ib = 0; ib < 4; ++ib) {
                avh[ib] = *(const short8*)(aHp[ib] + aoff);
                avl[ib] = *(const short8*)(aLp[ib] + aoff);
            }
            #pragma unroll
            for (int jb = 0; jb < 4; ++jb) {
                int mlocal = wpx * 64 + jb * 16 + ll;
                int cell = (2 * (mlocal >> 5) + kh) * 64 + 2 * (mlocal & 31) + kw;
                int ba = cell * 32 + ((qd ^ ((cell >> 1) & 3)) << 3);
                bvh[jb] = *(const short8*)&bldsH[ba];
                bvl[jb] = *(const short8*)&bldsL[ba];
            }
            __builtin_amdgcn_s_setprio(1);
            #pragma unroll
            for (int ib = 0; ib < 4; ++ib)
                #pragma unroll
                for (int jb = 0; jb < 4; ++jb) {
                    f32x4 o = acc[ib][jb];
                    o = __builtin_amdgcn_mfma_f32_16x16x32_bf16(avh[ib], bvh[jb], o, 0, 0, 0);
                    o = __builtin_amdgcn_mfma_f32_16x16x32_bf16(avl[ib], bvh[jb], o, 0, 0, 0);
                    o = __builtin_amdgcn_mfma_f32_16x16x32_bf16(avh[ib], bvl[jb], o, 0, 0, 0);
                    acc[ib][jb] = o;
                }
            __builtin_amdgcn_s_setprio(0);
        }
        __syncthreads();   // all taps done reading before next chunk restages
    }

    const int mbase = mt * 128 + wpx * 64;
    #pragma unroll
    for (int ib = 0; ib < 4; ++ib) {
        #pragma unroll
        for (int r = 0; r < 4; ++r) {
            int co = co0 + ib * 16 + qd * 4 + r;
            float bvv = bias[co];
            float* op = dst + (((size_t)((b0 + batl) * 256 + co)) << 10) + mbase + ll;
            #pragma unroll
            for (int jb = 0; jb < 4; ++jb)
                op[jb * 16] = acc[ib][jb][r] + bvv;
        }
    }
}

// ---------------------------------------------------------------------------
// GroupNorm stats (fp32 input): one block per (batch, group).
__global__ __launch_bounds__(256) void gn_stats_kernel(
    const float* __restrict__ buf, float* __restrict__ stats, int S)
{
    int bg = blockIdx.x;
    const float4* p = (const float4*)(buf + (size_t)bg * 8 * S);
    int n4 = 2 * S;
    float s = 0.f, s2 = 0.f;
    for (int i = threadIdx.x; i < n4; i += 256) {
        float4 vv = p[i];
        s  += vv.x + vv.y + vv.z + vv.w;
        s2 += vv.x * vv.x + vv.y * vv.y + vv.z * vv.z + vv.w * vv.w;
    }
    for (int d = 1; d < 64; d <<= 1) { s += __shfl_xor(s, d); s2 += __shfl_xor(s2, d); }
    __shared__ float red[8];
    int w = threadIdx.x >> 6;
    if ((threadIdx.x & 63) == 0) { red[w] = s; red[w + 4] = s2; }
    __syncthreads();
    if (threadIdx.x == 0) {
        s  = red[0] + red[1] + red[2] + red[3];
        s2 = red[4] + red[5] + red[6] + red[7];
        float invn = 1.f / (float)(8 * S);
        float mean = s * invn;
        float var = s2 * invn - mean * mean;
        if (var < 0.f) var = 0.f;
        stats[bg * 2]     = mean;
        stats[bg * 2 + 1] = 1.f / sqrtf(var + 1e-5f);
    }
}

// GroupNorm stats from bf16 hi/lo pair (q path) -> per-channel affine table
// ab[bat][c] = {a, bb} with a = scale*rstd, bb = bias - mean*a.
__global__ __launch_bounds__(256) void gn_stats_pair(
    const unsigned short* __restrict__ hi, const unsigned short* __restrict__ lo,
    const float* __restrict__ scale, const float* __restrict__ bias,
    float2* __restrict__ ab, int S)
{
    int bg = blockIdx.x;
    const uint4* ph = (const uint4*)(hi + (size_t)bg * 8 * S);
    const uint4* pl = (const uint4*)(lo + (size_t)bg * 8 * S);
    int n8 = S;
    float s = 0.f, s2 = 0.f;
    for (int i = threadIdx.x; i < n8; i += 256) {
        uint4 a = ph[i], b2 = pl[i];
        unsigned ua[4] = {a.x, a.y, a.z, a.w}, ub[4] = {b2.x, b2.y, b2.z, b2.w};
        #pragma unroll
        for (int j = 0; j < 4; ++j) {
            float x0 = __uint_as_float(ua[j] << 16) + __uint_as_float(ub[j] << 16);
            float x1 = __uint_as_float(ua[j] & 0xffff0000u) + __uint_as_float(ub[j] & 0xffff0000u);
            s += x0 + x1;
            s2 += x0 * x0 + x1 * x1;
        }
    }
    for (int d = 1; d < 64; d <<= 1) { s += __shfl_xor(s, d); s2 += __shfl_xor(s2, d); }
    __shared__ float red[8];
    __shared__ float mv[2];
    int w = threadIdx.x >> 6;
    if ((threadIdx.x & 63) == 0) { red[w] = s; red[w + 4] = s2; }
    __syncthreads();
    if (threadIdx.x == 0) {
        s  = red[0] + red[1] + red[2] + red[3];
        s2 = red[4] + red[5] + red[6] + red[7];
        float invn = 1.f / (float)(8 * S);
        float mean = s * invn;
        float var = s2 * invn - mean * mean;
        if (var < 0.f) var = 0.f;
        mv[0] = mean;
        mv[1] = 1.f / sqrtf(var + 1e-5f);
    }
    __syncthreads();
    if (threadIdx.x < 8) {
        int c = (bg & 31) * 8 + threadIdx.x;
        float a = scale[c] * mv[1];
        float bb = bias[c] - mv[0] * a;
        ab[(bg >> 5) * 256 + c] = make_float2(a, bb);
    }
}

// GN + affine + SiLU on fp32 v -> bf16 hi/lo pair, natural [C][M] layout.
__global__ __launch_bounds__(256) void gn_silu_split_v(
    const float* __restrict__ vf, unsigned short* __restrict__ hi,
    unsigned short* __restrict__ lo, const float* __restrict__ stats,
    const float* __restrict__ scale, const float* __restrict__ bias, int total8)
{
    int idx = blockIdx.x * 256 + threadIdx.x;
    if (idx >= total8) return;
    size_t e = (size_t)idx * 8;
    int c  = (int)((e >> 10) & 255);
    int gg = (int)(e >> 13);
    float mean = stats[gg * 2], rstd = stats[gg * 2 + 1];
    float a  = scale[c] * rstd;
    float bb = bias[c] - mean * a;
    float4 f0 = ((const float4*)vf)[idx * 2];
    float4 f1 = ((const float4*)vf)[idx * 2 + 1];
    float xs[8] = {f0.x, f0.y, f0.z, f0.w, f1.x, f1.y, f1.z, f1.w};
    unsigned oh[4], ol[4];
    #pragma unroll
    for (int j = 0; j < 4; ++j) {
        float y0 = xs[2 * j] * a + bb, y1 = xs[2 * j + 1] * a + bb;
        float s0 = y0 / (1.f + __expf(-y0));
        float s1 = y1 / (1.f + __expf(-y1));
        unsigned short h0 = f2bf(s0), l0 = f2bf(s0 - bf2f(h0));
        unsigned short h1 = f2bf(s1), l1 = f2bf(s1 - bf2f(h1));
        oh[j] = h0 | ((unsigned)h1 << 16);
        ol[j] = l0 | ((unsigned)l1 << 16);
    }
    ((uint4*)hi)[idx] = make_uint4(oh[0], oh[1], oh[2], oh[3]);
    ((uint4*)lo)[idx] = make_uint4(ol[0], ol[1], ol[2], ol[3]);
}

// GN + affine + SiLU on fp32 k -> TRANSPOSED bf16 hi/lo [B][M][C] (B-frag layout).
__global__ __launch_bounds__(256) void gn_silu_split_kT(
    const float* __restrict__ kf, unsigned short* __restrict__ th,
    unsigned short* __restrict__ tl, const float* __restrict__ stats,
    const float* __restrict__ scale, const float* __restrict__ bias)
{
    int bm = blockIdx.x;              // 8 batches * 128 m8-groups
    int b = bm >> 7, m8 = (bm & 127) * 8;
    int c = threadIdx.x;
    int gg = b * 32 + (c >> 3);
    float mean = stats[gg * 2], rstd = stats[gg * 2 + 1];
    float a  = scale[c] * rstd;
    float bb = bias[c] - mean * a;
    const float* src = kf + (((size_t)(b * 256 + c)) << 10) + m8;
    float4 f0 = *(const float4*)src;
    float4 f1 = *(const float4*)(src + 4);
    float xs[8] = {f0.x, f0.y, f0.z, f0.w, f1.x, f1.y, f1.z, f1.w};
    #pragma unroll
    for (int j = 0; j < 8; ++j) {
        float y = xs[j] * a + bb;
        float s = y / (1.f + __expf(-y));
        unsigned short h = f2bf(s), l = f2bf(s - bf2f(h));
        size_t o = ((size_t)b * M_ + m8 + j) * C_ + c;
        th[o] = h;
        tl[o] = l;
    }
}

// ---------------------------------------------------------------------------
// Fused flash attention, split-bf16 MFMA, LDS-STAGED K/V pipeline.
// Grid 512 = 8 bat x 64 nt (64 q-rows). Block 256 = 4 q-waves (16 rows each).
// q GroupNorm+SiLU fused into the one-time Q-frag load (ab table).
// V swizzle pi=(c>>1)&3: conflict-free ds_read_b128 per 8-lane group.
__global__ __launch_bounds__(256, 2) void attn_mfma(
    const unsigned short* __restrict__ qh, const unsigned short* __restrict__ qlo,
    const unsigned short* __restrict__ kth, const unsigned short* __restrict__ ktl,
    const unsigned short* __restrict__ vh, const unsigned short* __restrict__ vlo,
    const float2* __restrict__ abq,
    const float* __restrict__ gamma, float* __restrict__ out)
{
    __shared__ __align__(16) unsigned short kldsH[32 * 256];   // 16KB [m][Cg ^ (m&7)]
    __shared__ __align__(16) unsigned short kldsL[32 * 256];
    __shared__ __align__(16) unsigned short vldsH[256 * 32];   // 16KB [c][g ^ ((c>>1)&3)]
    __shared__ __align__(16) unsigned short vldsL[256 * 32];
    __shared__ __align__(16) unsigned short pH[4][16][40];
    __shared__ __align__(16) unsigned short pL[4][16][40];
    __shared__ float alphaS[4][16];

    int blk = blockIdx.x;
    int bat = blk & 7;
    int nt  = blk >> 3;           // 0..63
    int t = threadIdx.x;
    int w = t >> 6;               // q-wave 0..3
    int lane = t & 63;
    int ll = lane & 15;
    int qd = lane >> 4;
    int n0 = nt * 64 + w * 16;

    // Q A-frags: load raw conv output, apply GN+SiLU (+1/16 scale), split.
    short8 aqh[8], aql[8];
    {
        const unsigned short* qb1 = qh  + (size_t)bat * C_ * N_ + n0 + ll;
        const unsigned short* qb2 = qlo + (size_t)bat * C_ * N_ + n0 + ll;
        const float2* ab = abq + bat * 256;
        #pragma unroll
        for (int ks = 0; ks < 8; ++ks) {
            #pragma unroll
            for (int j = 0; j < 8; ++j) {
                int c = ks * 32 + qd * 8 + j;
                size_t off = (size_t)c * N_;
                float xv = bf2f(qb1[off]) + bf2f(qb2[off]);
                float2 t2 = ab[c];
                float yv = xv * t2.x + t2.y;
                float sv = 0.0625f * yv / (1.f + __expf(-yv));
                unsigned short h = f2bf(sv);
                aqh[ks][j] = (short)h;
                aql[ks][j] = (short)f2bf(sv - bf2f(h));
            }
        }
    }

    f32x4 oacc[16];
    #pragma unroll
    for (int i = 0; i < 16; ++i) oacc[i] = (f32x4){0.f, 0.f, 0.f, 0.f};
    f32x4 lacc = (f32x4){0.f, 0.f, 0.f, 0.f};
    float mrun[4] = {-3e38f, -3e38f, -3e38f, -3e38f};
    const short8 ones = (short8){16256, 16256, 16256, 16256, 16256, 16256, 16256, 16256};

    const unsigned short* kg = ((w & 1) == 0 ? kth : ktl) + (size_t)bat * M_ * C_;
    const unsigned short* vg = ((w & 1) == 0 ? vh  : vlo) + (size_t)bat * C_ * M_;
    unsigned short* kdst = (w & 1) ? kldsL : kldsH;
    unsigned short* vdst = (w & 1) ? vldsL : vldsH;
    const int krow  = lane >> 5;
    const int kcolg = lane & 31;
    const int vc_l  = lane >> 2;
    const int vg_g  = lane & 3;

    for (int mt = 0; mt < 32; ++mt) {
        const int m0 = mt * 32;
        if (w < 2) {
            #pragma unroll
            for (int i = 0; i < 16; ++i) {
                int row = 2 * i + krow;
                const unsigned short* src = kg + (size_t)(m0 + row) * 256
                                            + ((kcolg ^ (row & 7)) << 3);
                gl_lds16(src, kdst + i * 512);
            }
        } else {
            #pragma unroll
            for (int i = 0; i < 16; ++i) {
                int c = i * 16 + vc_l;
                const unsigned short* src = vg + (size_t)c * M_ + m0
                                            + ((vg_g ^ ((c >> 1) & 3)) << 3);
                gl_lds16(src, vdst + i * 512);
            }
        }
        __syncthreads();

        f32x4 s0 = {0.f, 0.f, 0.f, 0.f}, s1 = {0.f, 0.f, 0.f, 0.f};
        __builtin_amdgcn_s_setprio(1);
        #pragma unroll
        for (int ks = 0; ks < 8; ++ks) {
            int cg = ks * 4 + qd;
            int a0 = ll * 256 + ((cg ^ (ll & 7)) << 3);
            int a1 = (ll + 16) * 256 + ((cg ^ (ll & 7)) << 3);
            short8 b0h = *(const short8*)&kldsH[a0];
            short8 b1h = *(const short8*)&kldsH[a1];
            short8 b0l = *(const short8*)&kldsL[a0];
            short8 b1l = *(const short8*)&kldsL[a1];
            s0 = __builtin_amdgcn_mfma_f32_16x16x32_bf16(aqh[ks], b0h, s0, 0, 0, 0);
            s1 = __builtin_amdgcn_mfma_f32_16x16x32_bf16(aqh[ks], b1h, s1, 0, 0, 0);
            s0 = __builtin_amdgcn_mfma_f32_16x16x32_bf16(aql[ks], b0h, s0, 0, 0, 0);
            s1 = __builtin_amdgcn_mfma_f32_16x16x32_bf16(aql[ks], b1h, s1, 0, 0, 0);
            s0 = __builtin_amdgcn_mfma_f32_16x16x32_bf16(aqh[ks], b0l, s0, 0, 0, 0);
            s1 = __builtin_amdgcn_mfma_f32_16x16x32_bf16(aqh[ks], b1l, s1, 0, 0, 0);
        }
        __builtin_amdgcn_s_setprio(0);

        float alpha4[4];
        #pragma unroll
        for (int r = 0; r < 4; ++r) {
            float mx = fmaxf(s0[r], s1[r]);
            mx = fmaxf(mx, __shfl_xor(mx, 1));
            mx = fmaxf(mx, __shfl_xor(mx, 2));
            mx = fmaxf(mx, __shfl_xor(mx, 4));
            mx = fmaxf(mx, __shfl_xor(mx, 8));
            float mn = fmaxf(mrun[r], mx);
            float al = __expf(mrun[r] - mn);
            mrun[r] = mn;
            float p0 = __expf(s0[r] - mn);
            float p1 = __expf(s1[r] - mn);
            alpha4[r] = al;
            unsigned short h0 = f2bf(p0), l0 = f2bf(p0 - bf2f(h0));
            unsigned short h1 = f2bf(p1), l1 = f2bf(p1 - bf2f(h1));
            int rn = qd * 4 + r;
            pH[w][rn][ll] = h0;  pH[w][rn][16 + ll] = h1;
            pL[w][rn][ll] = l0;  pL[w][rn][16 + ll] = l1;
        }
        if (ll == 0) {
            #pragma unroll
            for (int r = 0; r < 4; ++r) alphaS[w][qd * 4 + r] = alpha4[r];
        }
        __builtin_amdgcn_wave_barrier();
        short8 bph = *(const short8*)&pH[w][ll][qd * 8];
        short8 bpl = *(const short8*)&pL[w][ll][qd * 8];
        float an = alphaS[w][ll];
        {
            f32x4 o = lacc;
            o[0] *= an; o[1] *= an; o[2] *= an; o[3] *= an;
            o = __builtin_amdgcn_mfma_f32_16x16x32_bf16(ones, bph, o, 0, 0, 0);
            o = __builtin_amdgcn_mfma_f32_16x16x32_bf16(ones, bpl, o, 0, 0, 0);
            lacc = o;
        }
        __builtin_amdgcn_s_setprio(1);
        #pragma unroll
        for (int ct = 0; ct < 16; ++ct) {
            int c = ct * 16 + ll;
            int av = c * 32 + ((qd ^ ((c >> 1) & 3)) << 3);
            short8 avh = *(const short8*)&vldsH[av];
            short8 avl = *(const short8*)&vldsL[av];
            f32x4 o = oacc[ct];
            o[0] *= an; o[1] *= an; o[2] *= an; o[3] *= an;
            o = __builtin_amdgcn_mfma_f32_16x16x32_bf16(avh, bph, o, 0, 0, 0);
            o = __builtin_amdgcn_mfma_f32_16x16x32_bf16(avl, bph, o, 0, 0, 0);
            o = __builtin_amdgcn_mfma_f32_16x16x32_bf16(avh, bpl, o, 0, 0, 0);
            oacc[ct] = o;
        }
        __builtin_amdgcn_s_setprio(0);
        __syncthreads();
    }

    float linv = gamma[0] / lacc[0];
    float* ob = out + (size_t)bat * C_ * N_ + n0 + ll;
    #pragma unroll
    for (int ct = 0; ct < 16; ++ct) {
        #pragma unroll
        for (int r = 0; r < 4; ++r) {
            int c = ct * 16 + qd * 4 + r;
            ob[(size_t)c * N_] = oacc[ct][r] * linv;
        }
    }
}

// ---------------------------------------------------------------------------
extern "C" void kernel_launch(void* const* d_in, const int* in_sizes, int n_in,
                              void* d_out, int out_size, void* d_ws, size_t ws_size,
                              hipStream_t stream)
{
    const float* x   = (const float*)d_in[0];
    const float* y   = (const float*)d_in[1];
    const float* Wq  = (const float*)d_in[2];
    const float* bq  = (const float*)d_in[3];
    const float* gqs = (const float*)d_in[4];
    const float* gqb = (const float*)d_in[5];
    const float* Wk  = (const float*)d_in[6];
    const float* bk  = (const float*)d_in[7];
    const float* gks = (const float*)d_in[8];
    const float* gkb = (const float*)d_in[9];
    const float* Wv  = (const float*)d_in[10];
    const float* bv  = (const float*)d_in[11];
    const float* gvs = (const float*)d_in[12];
    const float* gvb = (const float*)d_in[13];
    const float* gamma = (const float*)d_in[14];
    float* out = (float*)d_out;

    // ws layout (71.6 MB total, all phases):
    //   qH, qL: 2 x 16.78 MB (raw conv3x3 output; GN+SiLU applied in attn)
    //   regA (phase-overlaid, 38.05 MB)
    char* base = (char*)d_ws;
    unsigned short* qH = (unsigned short*)base;
    unsigned short* qL = qH + 8388608;
    char* regA = (char*)(qL + 8388608);
    // conv3 overlay
    unsigned short* xpH = (unsigned short*)regA;      // 8,921,088 shorts
    unsigned short* xpL = xpH + 8921088;
    unsigned short* wtH = xpL + 8921088;              // 589,824 shorts
    unsigned short* wtL = wtH + 589824;
    // pipeline overlay
    float* kf = (float*)regA;                         // 2,097,152 floats
    float* vf = kf + 2097152;
    unsigned short* kTh = (unsigned short*)(vf + 2097152);
    unsigned short* kTl = kTh + 2097152;
    unsigned short* vH  = kTl + 2097152;
    unsigned short* vL  = vH + 2097152;
    float* stq = (float*)(vL + 2097152);
    float* stk = stq + 512;
    float* stv = stk + 512;
    float2* abq = (float2*)(stv + 512);               // 8*256 float2 = 16KB
    // conv2 overlay (after kf,vf; dead once conv2x2_mfma finishes)
    unsigned short* yTh  = (unsigned short*)(vf + 2097152);   // 4,194,304 shorts (4 bat)
    unsigned short* yTl  = yTh + 4194304;
    unsigned short* w2kH = yTl + 4194304;                     // 262,144 shorts each
    unsigned short* w2kL = w2kH + 262144;
    unsigned short* w2vH = w2kL + 262144;
    unsigned short* w2vL = w2vH + 262144;

    // conv3x3 (q path) via MFMA (LDS-staged operands)
    hipMemsetAsync(xpH, 0, (size_t)2 * 8921088 * sizeof(unsigned short), stream);
    split_w_tap<<<256, 256, 0, stream>>>(Wq, wtH, wtL);
    split_x_pad<<<512, 256, 0, stream>>>(x, xpH, xpL);
    conv3x3_mfma<<<512, 256, 0, stream>>>(xpH, xpL, wtH, wtL, bq, qH, qL);

    // conv2x2 (k,v) via MFMA (LDS-staged B), two 4-batch halves.
    split_w2<<<256, 256, 0, stream>>>(Wk, w2kH, w2kL);
    split_w2<<<256, 256, 0, stream>>>(Wv, w2vH, w2vL);
    split_y_t<<<256, 256, 0, stream>>>(y, yTh, yTl, 0);
    conv2x2_mfma<<<128, 256, 0, stream>>>(yTh, yTl, w2kH, w2kL, w2vH, w2vL,
                                          bk, bv, kf, vf, 0);
    split_y_t<<<256, 256, 0, stream>>>(y, yTh, yTl, 4);
    conv2x2_mfma<<<128, 256, 0, stream>>>(yTh, yTl, w2kH, w2kL, w2vH, w2vL,
                                          bk, bv, kf, vf, 4);

    gn_stats_pair<<<256, 256, 0, stream>>>(qH, qL, gqs, gqb, abq, 4096);
    gn_stats_kernel<<<256, 256, 0, stream>>>(kf, stk, 1024);
    gn_stats_kernel<<<256, 256, 0, stream>>>(vf, stv, 1024);
    gn_silu_split_v<<<1024, 256, 0, stream>>>(vf, vH, vL, stv, gvs, gvb, 262144);
    gn_silu_split_kT<<<1024, 256, 0, stream>>>(kf, kTh, kTl, stk, gks, gkb);
    attn_mfma<<<512, 256, 0, stream>>>(qH, qL, kTh, kTl, vH, vL, abq, gamma, out);
}